// Round 7
// baseline (2707.713 us; speedup 1.0000x reference)
//
#include <hip/hip_runtime.h>
#include <hip/hip_bf16.h>

typedef unsigned short u16;
typedef __attribute__((ext_vector_type(8))) short bf16x8;
typedef __attribute__((ext_vector_type(4))) float f32x4;

typedef __attribute__((address_space(1))) const void gv_t;  // global
typedef __attribute__((address_space(3))) void lv_t;        // LDS

#define DEVINL __device__ __forceinline__

DEVINL float bf2f(u16 s) { union { unsigned u; float f; } v; v.u = ((unsigned)s) << 16; return v.f; }
DEVINL u16 f2bf(float f) {
  union { float f; unsigned u; } v; v.f = f;
  return (u16)((v.u + 0x7FFFu + ((v.u >> 16) & 1u)) >> 16);
}

// ---- ws probe ----
__global__ void probe_k(float* __restrict__ out, float v) { out[threadIdx.x] = v; }

// ---- batched layer-2 packs: 5 jobs x 1024 blocks ----
struct PackPtrs { const float* wl2; const float* wr2; u16* bt[5]; };
__global__ __launch_bounds__(256) void pack_multi(PackPtrs p) {
  int j = blockIdx.x >> 10;
  int idx = (blockIdx.x & 1023) * 256 + threadIdx.x;
  int k = idx >> 9, n = idx & 511;
  float v;
  if (j < 4) {
    int r = (j == 3) ? 4 : j;
    v = p.wl2[((size_t)r * 512 + k) * 512 + n];
  } else {
    size_t o = (size_t)k * 512 + n;
    v = p.wr2[o] + p.wr2[o + 262144] + p.wr2[o + 524288] + p.wr2[o + 1048576];
  }
  p.bt[j][(size_t)n * 512 + k] = f2bf(v * 0.25f);
}

// ================= batched layer-1 weight folding (18 jobs) =================
struct FoldPtrs { const float* a[8]; const float* w[2]; u16* bt[4]; };
__constant__ int   c_off[19] = {0,16,24,56,64,320,328,360,368,400,416,424,440,696,704,960,1216,1224,1256};
__constant__ int   c_ai[18]  = {0,1,2,3,4,5,6,7,6, 0,1,0, 4,5,4, 4,5,2};
__constant__ int   c_wi[18]  = {0,0,0,0,0,0,0,0,1, 0,0,1, 0,0,1, 0,0,1};
__constant__ int   c_r0[18]  = {0,0,1,1,2,2,4,4,0, 5,5,5, 6,6,6, 3,3,3};
__constant__ float c_sc[18]  = {0.25f,0.25f,0.25f,0.25f,0.25f,0.25f,0.25f,0.25f,0.25f,
                                1.f,1.f,1.f, 1.f,1.f,1.f, 1.f,1.f,1.f};
__constant__ int   c_bt[18]  = {0,0,0,0,0,0,0,0,0, 1,1,1, 2,2,2, 3,3,3};
__constant__ int   c_K[18]   = {64,64,64,64,64,64,64,64,64, 64,64,64, 128,128,128, 64,64,64};
__constant__ int   c_ko[18]  = {0,2,3,7,8,40,41,45,46, 0,2,3, 0,32,33, 0,32,33};

__global__ __launch_bounds__(256) void fold_multi(FoldPtrs p) {
  __shared__ float red[256];
  int b = blockIdx.x;
  int j = 0;
#pragma unroll
  for (int t = 1; t < 18; ++t) j += (b >= c_off[t]);
  int rel = b - c_off[j];
  int f = rel >> 3, nb = rel & 7;
  int tid = threadIdx.x;
  int n = nb * 64 + (tid & 63);
  int kg = tid >> 6;
  const float* A = p.a[c_ai[j]] + (size_t)f * 512;
  const float* W = p.w[c_wi[j]];
  int k0 = kg * 128;
  float acc = 0.f;
  if (j != 8) {
    const float* Wp = W + (size_t)c_r0[j] * 512 * 512 + n;
#pragma unroll 16
    for (int k = k0; k < k0 + 128; ++k) acc += A[k] * Wp[(size_t)k * 512];
  } else {
    const float* W0 = W + n;
    const float* W1 = W + (size_t)262144 + n;
    const float* W2 = W + (size_t)524288 + n;
    const float* W4 = W + (size_t)1048576 + n;
#pragma unroll 8
    for (int k = k0; k < k0 + 128; ++k) {
      size_t o = (size_t)k * 512;
      acc += A[k] * (W0[o] + W1[o] + W2[o] + W4[o]);
    }
  }
  red[tid] = acc;
  __syncthreads();
  if (kg == 0) {
    float v = red[tid] + red[tid + 64] + red[tid + 128] + red[tid + 192];
    p.bt[c_bt[j]][(size_t)n * c_K[j] + c_ko[j] + f] = f2bf(v * c_sc[j]);
  }
}

// ---- batched bias folds ----
struct VFPtrs { const float* bl[5]; const float* bvec[5]; const float* w; float* out[5]; };
__constant__ int   c_vi[5][4] = {{0,1,2,4},{0,1,2,4},{5,-1,-1,-1},{6,-1,-1,-1},{3,-1,-1,-1}};
__constant__ float c_vs[5]    = {0.25f,0.25f,1.f,1.f,1.f};

__global__ __launch_bounds__(256) void vecfold_multi(VFPtrs p) {
  __shared__ float red[256];
  int j = blockIdx.x >> 4, blk = blockIdx.x & 15;
  int tid = threadIdx.x;
  int n = blk * 32 + (tid & 31);
  int kg = tid >> 5;
  const float* bv = p.bvec[j];
  float a = 0.f;
  if (bv) {
    int i1 = c_vi[j][1];
    const float* W0 = p.w + (size_t)c_vi[j][0] * 262144 + n;
    if (i1 < 0) {
#pragma unroll 16
      for (int k = kg * 64; k < kg * 64 + 64; ++k) a += bv[k] * W0[(size_t)k * 512];
    } else {
      const float* W1 = p.w + (size_t)c_vi[j][1] * 262144 + n;
      const float* W2 = p.w + (size_t)c_vi[j][2] * 262144 + n;
      const float* W3 = p.w + (size_t)c_vi[j][3] * 262144 + n;
#pragma unroll 8
      for (int k = kg * 64; k < kg * 64 + 64; ++k) {
        size_t o = (size_t)k * 512;
        a += bv[k] * (W0[o] + W1[o] + W2[o] + W3[o]);
      }
    }
  }
  red[tid] = a;
  __syncthreads();
  if (kg == 0) {
    float v = 0.f;
#pragma unroll
    for (int q = 0; q < 8; ++q) v += red[(tid & 31) + q * 32];
    float bsum = p.bl[j][c_vi[j][0] * 512 + n];
    if (c_vi[j][1] >= 0) {
      bsum += p.bl[j][c_vi[j][1] * 512 + n];
      bsum += p.bl[j][c_vi[j][2] * 512 + n];
      bsum += p.bl[j][c_vi[j][3] * 512 + n];
    }
    p.out[j][n] = (v + bsum) * c_vs[j];
  }
}

// ================= CSR build (batched) =================
struct EdgePtrs { const int* dst[7]; const int* src[7]; };
__constant__ int c_hoff[8]  = {0,1024,2048,3072,4096,5120,5248,5760};
__constant__ int c_hbase[7] = {0,131072,262144,393216,458752,589824,622592};
__constant__ int c_hne[7]   = {262144,262144,262144,262144,262144,32768,131072};

__global__ __launch_bounds__(256) void hist_multi(EdgePtrs p, int* __restrict__ cnt) {
  int b = blockIdx.x;
  int j = 0;
#pragma unroll
  for (int t = 1; t < 7; ++t) j += (b >= c_hoff[t]);
  int i = (b - c_hoff[j]) * 256 + threadIdx.x;
  if (i < c_hne[j]) atomicAdd(&cnt[c_hbase[j] + p.dst[j][i]], 1);
}

__global__ __launch_bounds__(256) void fill_multi(EdgePtrs p, int* __restrict__ cursor,
                                                  int* __restrict__ esrc) {
  int b = blockIdx.x;
  int j = 0;
#pragma unroll
  for (int t = 1; t < 7; ++t) j += (b >= c_hoff[t]);
  int i = (b - c_hoff[j]) * 256 + threadIdx.x;
  if (i < c_hne[j]) {
    int pos = atomicAdd(&cursor[c_hbase[j] + p.dst[j][i]], 1);
    esrc[pos] = p.src[j][i];
  }
}

// filtered CSRs: 4 jobs (rel2 h0, rel2 h1, rel4 h0, rel4 h1), 1024 blocks each
struct FiltPtrs { const int* dst[2]; const int* src[2]; };
__global__ __launch_bounds__(256) void histf_multi(FiltPtrs p, int* __restrict__ cnt) {
  int j = blockIdx.x >> 10;
  int rel = j >> 1, s0 = (j & 1) * 65536;
  int i = (blockIdx.x & 1023) * 256 + threadIdx.x;
  int s = p.src[rel][i];
  if (s >= s0 && s < s0 + 65536) atomicAdd(&cnt[j * 131072 + p.dst[rel][i]], 1);
}
__global__ __launch_bounds__(256) void fillf_multi(FiltPtrs p, int* __restrict__ cursor,
                                                   int* __restrict__ esrc) {
  int j = blockIdx.x >> 10;
  int rel = j >> 1, s0 = (j & 1) * 65536;
  int i = (blockIdx.x & 1023) * 256 + threadIdx.x;
  int s = p.src[rel][i];
  if (s >= s0 && s < s0 + 65536) {
    int pos = atomicAdd(&cursor[j * 131072 + p.dst[rel][i]], 1);
    esrc[pos] = s - s0;
  }
}

__global__ void scan1_k(const int* __restrict__ in, int* __restrict__ out,
                        int* __restrict__ part, int n) {
  __shared__ int s[256];
  int t = threadIdx.x;
  int base = blockIdx.x * 1024 + t * 4;
  int x0 = 0, x1 = 0, x2 = 0, x3 = 0;
  if (base < n) x0 = in[base];
  if (base + 1 < n) x1 = in[base + 1];
  if (base + 2 < n) x2 = in[base + 2];
  if (base + 3 < n) x3 = in[base + 3];
  int tsum = x0 + x1 + x2 + x3;
  s[t] = tsum;
  __syncthreads();
  for (int off = 1; off < 256; off <<= 1) {
    int v = (t >= off) ? s[t - off] : 0;
    __syncthreads();
    s[t] += v;
    __syncthreads();
  }
  int excl = s[t] - tsum;
  if (base < n) out[base] = excl;
  if (base + 1 < n) out[base + 1] = excl + x0;
  if (base + 2 < n) out[base + 2] = excl + x0 + x1;
  if (base + 3 < n) out[base + 3] = excl + x0 + x1 + x2;
  if (t == 255) part[blockIdx.x] = s[255];
}

__global__ void scan2_k(int* __restrict__ part, int nb) {
  __shared__ int s[1024];
  int t = threadIdx.x;
  int orig = (t < nb) ? part[t] : 0;
  s[t] = orig;
  __syncthreads();
  for (int off = 1; off < 1024; off <<= 1) {
    int v = (t >= off) ? s[t - off] : 0;
    __syncthreads();
    s[t] += v;
    __syncthreads();
  }
  if (t < nb) part[t] = s[t] - orig;
}

__global__ void scan3_k(int* __restrict__ out, int* __restrict__ cursor,
                        const int* __restrict__ part, int n) {
  int i = blockIdx.x * 256 + threadIdx.x;
  if (i < n) {
    int v = out[i] + part[i >> 10];
    out[i] = v;
    cursor[i] = v;
  }
}

// ---- raw-feature segment mean + indicator (8 threads per dst row) ----
__global__ void raw_agg(const int* __restrict__ offs, const int* __restrict__ esrc,
                        const float* __restrict__ x, int F, u16* __restrict__ A1,
                        int K, int colOff, int indCol, int nd) {
  int row = blockIdx.x * 32 + (threadIdx.x >> 3);
  if (row >= nd) return;
  int j = threadIdx.x & 7;
  int e0 = offs[row], e1 = offs[row + 1];
  float acc[4] = {0.f, 0.f, 0.f, 0.f};
  for (int e = e0; e < e1; ++e) {
    int s = esrc[e];
#pragma unroll
    for (int u = 0; u < 4; ++u) {
      int f = j + u * 8;
      if (f < F) acc[u] += x[(size_t)s * F + f];
    }
  }
  float inv = (e1 > e0) ? 1.f / (float)(e1 - e0) : 0.f;
#pragma unroll
  for (int u = 0; u < 4; ++u) {
    int f = j + u * 8;
    if (f < F) A1[(size_t)row * K + colOff + f] = f2bf(acc[u] * inv);
  }
  if (j == 0) A1[(size_t)row * K + indCol] = f2bf((e1 > e0) ? 1.f : 0.f);
}

// batched version for stage G: 4 jobs x 2048 blocks, K=64, nd=65536
struct RawPtrs { const int* offs; const int* esrc; const float* x[4]; u16* A1; };
__constant__ int c_gF[4]    = {2,4,32,4};
__constant__ int c_gco[4]   = {0,3,8,41};
__constant__ int c_gic[4]   = {2,7,40,45};
__constant__ int c_gcsrb[4] = {0,131072,262144,458752};

__global__ __launch_bounds__(256) void raw_multi(RawPtrs p, int s0) {
  int j = blockIdx.x >> 11;
  int row = (blockIdx.x & 2047) * 32 + (threadIdx.x >> 3);
  int jj = threadIdx.x & 7;
  const int* offs = p.offs + c_gcsrb[j] + s0;
  const float* x = p.x[j];
  int F = c_gF[j];
  int e0 = offs[row], e1 = offs[row + 1];
  float acc[4] = {0.f, 0.f, 0.f, 0.f};
  for (int e = e0; e < e1; ++e) {
    int s = p.esrc[e];
#pragma unroll
    for (int u = 0; u < 4; ++u) {
      int f = jj + u * 8;
      if (f < F) acc[u] += x[(size_t)s * F + f];
    }
  }
  float inv = (e1 > e0) ? 1.f / (float)(e1 - e0) : 0.f;
#pragma unroll
  for (int u = 0; u < 4; ++u) {
    int f = jj + u * 8;
    if (f < F) p.A1[(size_t)row * 64 + c_gco[j] + f] = f2bf(acc[u] * inv);
  }
  if (jj == 0) p.A1[(size_t)row * 64 + c_gic[j]] = f2bf((e1 > e0) ? 1.f : 0.f);
}

// ---- copy root raw features into A1 ----
__global__ void a1_root(const float* __restrict__ x, int rowBase, u16* __restrict__ A1,
                        int K, int rootOff, int nd, int lf) {
  int idx = blockIdx.x * 256 + threadIdx.x;
  int i = idx >> lf, f = idx & ((1 << lf) - 1);
  if (i >= nd) return;
  A1[(size_t)i * K + rootOff + f] = f2bf(x[(((size_t)(rowBase + i)) << lf) + f]);
}

// ================= fused gather + accumulate GEMM =================
// Block: 64 output rows x 512 cols, K=512. Phase 1: segment-mean gather into
// swizzled LDS A-tile (64 KB). Phase 2: MFMA, B read direct from L2, bf16 RMW on C.
template <bool FIRST>
__global__ __launch_bounds__(256) void fgemm_k(
    const int* __restrict__ offsF, const int* __restrict__ offsS,
    const int* __restrict__ esrcF, const u16* __restrict__ hsrc,
    const u16* __restrict__ BT, const float* __restrict__ bias,
    u16* __restrict__ C) {
  __shared__ u16 As[64 * 512];  // 64 KiB
  int tid = threadIdx.x;
  int w = tid >> 6, lane = tid & 63;
  int r16 = lane & 15, hi4 = lane >> 4;
  int bm = blockIdx.x * 64;

  // ---- phase 1: gather 16 rows per wave ----
#pragma unroll 1
  for (int rr = 0; rr < 16; ++rr) {
    int row = w * 16 + rr;
    int gr = bm + row;
    int e0 = offsF[gr], e1 = offsF[gr + 1];
    int cc0 = offsS[gr], cc1 = offsS[gr + 1];
    float inv = (cc1 > cc0) ? 1.f / (float)(cc1 - cc0) : 0.f;
    float a[8] = {0.f, 0.f, 0.f, 0.f, 0.f, 0.f, 0.f, 0.f};
    for (int e = e0; e < e1; ++e) {
      int s = esrcF[e];
      bf16x8 v = *(const bf16x8*)&hsrc[(size_t)s * 512 + lane * 8];
#pragma unroll
      for (int j = 0; j < 8; ++j) a[j] += bf2f((u16)v[j]);
    }
    bf16x8 r;
#pragma unroll
    for (int j = 0; j < 8; ++j) r[j] = (short)f2bf(a[j] * inv);
    *(bf16x8*)&As[row * 512 + ((lane ^ (row & 7)) << 3)] = r;
  }
  __syncthreads();

  // ---- phase 2: GEMM. wave w -> cols [w*128, +128), rows [0,64) ----
  f32x4 acc[4][8];
#pragma unroll
  for (int mf = 0; mf < 4; ++mf)
#pragma unroll
    for (int nf = 0; nf < 8; ++nf) acc[mf][nf] = (f32x4){0.f, 0.f, 0.f, 0.f};
  int sw = r16 & 7;
#pragma unroll
  for (int k32 = 0; k32 < 512; k32 += 32) {
    bf16x8 af[4], bfr[8];
#pragma unroll
    for (int mf = 0; mf < 4; ++mf) {
      int g = (k32 >> 3) + hi4;
      af[mf] = *(const bf16x8*)&As[(mf * 16 + r16) * 512 + ((g ^ sw) << 3)];
    }
#pragma unroll
    for (int nf = 0; nf < 8; ++nf)
      bfr[nf] = *(const bf16x8*)&BT[(size_t)(w * 128 + nf * 16 + r16) * 512 + k32 + hi4 * 8];
#pragma unroll
    for (int mf = 0; mf < 4; ++mf)
#pragma unroll
      for (int nf = 0; nf < 8; ++nf)
        acc[mf][nf] = __builtin_amdgcn_mfma_f32_16x16x32_bf16(af[mf], bfr[nf], acc[mf][nf], 0, 0, 0);
  }
  // ---- epilogue: bf16 RMW (or bias-init when FIRST) ----
#pragma unroll
  for (int mf = 0; mf < 4; ++mf) {
#pragma unroll
    for (int nf = 0; nf < 8; ++nf) {
      int c = w * 128 + nf * 16 + r16;
      float bv = FIRST ? bias[c] : 0.f;
#pragma unroll
      for (int j = 0; j < 4; ++j) {
        int r = bm + mf * 16 + hi4 * 4 + j;
        float v = acc[mf][nf][j] + bv;
        if (!FIRST) v += bf2f(C[(size_t)r * 512 + c]);
        C[(size_t)r * 512 + c] = f2bf(v);
      }
    }
  }
}

// ---- MFMA GEMM (layer-1 + root): C[M][512] (+)= op(A[M][K] @ BT^T + bias) ----
template <bool ELU, bool ACC, int K>
__global__ __launch_bounds__(256) void gemm_k(
    const u16* __restrict__ A, const u16* __restrict__ BT,
    const float* __restrict__ bias, u16* __restrict__ C, int M) {
  __shared__ u16 As[128 * 64];
  __shared__ u16 Bs[128 * 64];
  int tid = threadIdx.x;
  int wid = tid >> 6, lane = tid & 63;
  int wm = wid >> 1, wn = wid & 1;
  int bm = blockIdx.x * 128, bn = blockIdx.y * 128;
  int r16 = lane & 15, hi4 = lane >> 4;
  int srow = tid >> 3;
  int scol = ((tid & 7) ^ (srow & 7)) * 8;
  int sw = r16 & 7;
  f32x4 acc[4][4];
#pragma unroll
  for (int i = 0; i < 4; ++i)
#pragma unroll
    for (int j = 0; j < 4; ++j) acc[i][j] = (f32x4){0.f, 0.f, 0.f, 0.f};

#pragma unroll
  for (int k0 = 0; k0 < K; k0 += 64) {
    __syncthreads();
#pragma unroll
    for (int i = 0; i < 4; ++i) {
      const u16* ga = A + (size_t)(bm + i * 32 + srow) * K + k0 + scol;
      const u16* gb = BT + (size_t)(bn + i * 32 + srow) * K + k0 + scol;
      __builtin_amdgcn_global_load_lds((gv_t*)ga, (lv_t*)(As + i * 2048 + wid * 512), 16, 0, 0);
      __builtin_amdgcn_global_load_lds((gv_t*)gb, (lv_t*)(Bs + i * 2048 + wid * 512), 16, 0, 0);
    }
    __syncthreads();
#pragma unroll
    for (int kk = 0; kk < 64; kk += 32) {
      bf16x8 af[4], bfr[4];
#pragma unroll
      for (int f = 0; f < 4; ++f) {
        int grp = (kk >> 3) + hi4;
        af[f]  = *(const bf16x8*)&As[(wm * 64 + f * 16 + r16) * 64 + ((grp ^ sw) << 3)];
        bfr[f] = *(const bf16x8*)&Bs[(wn * 64 + f * 16 + r16) * 64 + ((grp ^ sw) << 3)];
      }
#pragma unroll
      for (int mf = 0; mf < 4; ++mf)
#pragma unroll
        for (int nf = 0; nf < 4; ++nf)
          acc[mf][nf] = __builtin_amdgcn_mfma_f32_16x16x32_bf16(af[mf], bfr[nf], acc[mf][nf], 0, 0, 0);
    }
  }
#pragma unroll
  for (int mf = 0; mf < 4; ++mf) {
#pragma unroll
    for (int nf = 0; nf < 4; ++nf) {
      int c = bn + wn * 64 + nf * 16 + r16;
      float bv = bias ? bias[c] : 0.f;
#pragma unroll
      for (int j = 0; j < 4; ++j) {
        int r = bm + wm * 64 + mf * 16 + hi4 * 4 + j;
        float v = acc[mf][nf][j] + bv;
        if (ACC) v += bf2f(C[(size_t)r * 512 + c]);
        if (ELU) v = v > 0.f ? v : expm1f(v);
        C[(size_t)r * 512 + c] = f2bf(v);
      }
    }
  }
}

// ---- LayerNorm in place (wave per row) ----
__global__ void ln_rows(u16* __restrict__ H, const float* __restrict__ g,
                        const float* __restrict__ be, int rows) {
  int w = blockIdx.x * 4 + (threadIdx.x >> 6);
  if (w >= rows) return;
  int l = threadIdx.x & 63;
  u16* p = H + (size_t)w * 512 + l * 8;
  bf16x8 v = *(const bf16x8*)p;
  float x[8];
  float s = 0.f;
#pragma unroll
  for (int j = 0; j < 8; ++j) { x[j] = bf2f((u16)v[j]); s += x[j]; }
#pragma unroll
  for (int m = 1; m < 64; m <<= 1) s += __shfl_xor(s, m, 64);
  float mean = s * (1.f / 512.f);
  float q = 0.f;
#pragma unroll
  for (int j = 0; j < 8; ++j) { float d = x[j] - mean; q += d * d; }
#pragma unroll
  for (int m = 1; m < 64; m <<= 1) q += __shfl_xor(q, m, 64);
  float rsd = rsqrtf(q * (1.f / 512.f) + 1e-5f);
  bf16x8 r;
#pragma unroll
  for (int j = 0; j < 8; ++j) {
    int c = l * 8 + j;
    r[j] = (short)f2bf((x[j] - mean) * rsd * g[c] + be[c]);
  }
  *(bf16x8*)p = r;
}

// ---- fused ELU + LN2 + pool partial-sum ----
DEVINL int lowb(const int* a, int n, int v) {
  int lo = 0, hi = n;
  while (lo < hi) { int m = (lo + hi) >> 1; if (a[m] < v) lo = m + 1; else hi = m; }
  return lo;
}

__global__ __launch_bounds__(256) void pool1v(const u16* __restrict__ H,
                                              const int* __restrict__ batch, int nOp,
                                              const float* __restrict__ g2,
                                              const float* __restrict__ be2,
                                              float* __restrict__ pooled,
                                              int* __restrict__ cnts) {
  __shared__ float red[4][512];
  int gr = blockIdx.x >> 4, part = blockIdx.x & 15;
  int lo = lowb(batch, nOp, gr), hi = lowb(batch, nOp, gr + 1);
  if (part == 0 && threadIdx.x == 0) cnts[gr] = hi - lo;
  int len = hi - lo;
  int chunk = (len + 15) >> 4;
  int r0 = lo + part * chunk;
  int r1 = r0 + chunk;
  if (r1 > hi) r1 = hi;
  int wv = threadIdx.x >> 6, l = threadIdx.x & 63;
  float a[8] = {0.f, 0.f, 0.f, 0.f, 0.f, 0.f, 0.f, 0.f};
  float gv[8], bv[8];
#pragma unroll
  for (int j = 0; j < 8; ++j) { gv[j] = g2[l * 8 + j]; bv[j] = be2[l * 8 + j]; }
  for (int r = r0 + wv; r < r1; r += 4) {
    bf16x8 v = *(const bf16x8*)&H[(size_t)r * 512 + l * 8];
    float x[8];
    float s = 0.f;
#pragma unroll
    for (int j = 0; j < 8; ++j) {
      x[j] = bf2f((u16)v[j]);
      x[j] = x[j] > 0.f ? x[j] : expm1f(x[j]);
      s += x[j];
    }
#pragma unroll
    for (int m = 1; m < 64; m <<= 1) s += __shfl_xor(s, m, 64);
    float mean = s * (1.f / 512.f);
    float q = 0.f;
#pragma unroll
    for (int j = 0; j < 8; ++j) { float d = x[j] - mean; q += d * d; }
#pragma unroll
    for (int m = 1; m < 64; m <<= 1) q += __shfl_xor(q, m, 64);
    float rsd = rsqrtf(q * (1.f / 512.f) + 1e-5f);
#pragma unroll
    for (int j = 0; j < 8; ++j) a[j] += (x[j] - mean) * rsd * gv[j] + bv[j];
  }
#pragma unroll
  for (int j = 0; j < 8; ++j) red[wv][l * 8 + j] = a[j];
  __syncthreads();
  if (wv == 0) {
#pragma unroll
    for (int j = 0; j < 8; ++j) {
      int c = l * 8 + j;
      float s = red[0][c] + red[1][c] + red[2][c] + red[3][c];
      atomicAdd(&pooled[gr * 512 + c], s);
    }
  }
}

__global__ void pool2(const float* __restrict__ pooled, const int* __restrict__ cnts,
                      const float* __restrict__ Wout, const float* __restrict__ bout,
                      float* __restrict__ out) {
  int gg = blockIdx.x;
  int l = threadIdx.x;
  float s = 0.f;
#pragma unroll
  for (int j = 0; j < 8; ++j) {
    int c = l * 8 + j;
    s += pooled[gg * 512 + c] * Wout[c];
  }
#pragma unroll
  for (int m = 1; m < 64; m <<= 1) s += __shfl_xor(s, m, 64);
  if (l == 0) {
    int c = cnts[gg];
    if (c < 1) c = 1;
    out[gg] = s / (float)c + bout[0];
  }
}

extern "C" void kernel_launch(void* const* d_in, const int* in_sizes, int n_in,
                              void* d_out, int out_size, void* d_ws, size_t ws_size,
                              hipStream_t stream) {
  (void)in_sizes; (void)n_in; (void)out_size;
  const float* x_op   = (const float*)d_in[0];
  const float* x_tab  = (const float*)d_in[1];
  const float* x_col  = (const float*)d_in[2];
  const float* x_pred = (const float*)d_in[3];
  const float* W_op = (const float*)d_in[4],  *b_op = (const float*)d_in[5];
  const float* W_tab = (const float*)d_in[6], *b_tab = (const float*)d_in[7];
  const float* W_col = (const float*)d_in[8], *b_col = (const float*)d_in[9];
  const float* W_pred = (const float*)d_in[10], *b_pred = (const float*)d_in[11];
  const float* Wl1 = (const float*)d_in[12];
  const float* bl1 = (const float*)d_in[13];
  const float* Wr1 = (const float*)d_in[14];
  const float* Wl2 = (const float*)d_in[15];
  const float* bl2 = (const float*)d_in[16];
  const float* Wr2 = (const float*)d_in[17];
  const float* g1  = (const float*)d_in[18];
  const float* be1 = (const float*)d_in[19];
  const float* g2  = (const float*)d_in[20];
  const float* be2 = (const float*)d_in[21];
  const float* Wout = (const float*)d_in[22];
  const float* bout = (const float*)d_in[23];
  const int* SRC[7], *DST[7];
  for (int r = 0; r < 7; ++r) { SRC[r] = (const int*)d_in[24 + 2 * r]; DST[r] = (const int*)d_in[25 + 2 * r]; }
  const int* batch = (const int*)d_in[38];
  float* out = (float*)d_out;

  const int CSRB[7] = {0, 131072, 262144, 393216, 458752, 589824, 622592};
  const int TOT = 753664;
  const int NOP = 131072;

  // ---- workspace layout (256 MiB) ----
  char* ws = (char*)d_ws;
  u16* acc     = (u16*)ws;                          // 134,217,728
  u16* hsrc    = (u16*)(ws + 134217728ull);         //  67,108,864
  int* curFul  = (int*)(ws + 201326592ull);         //  (TOT+1)*4
  int* curAll  = (int*)(ws + 204341504ull);         //  524,289*4
  u16* A1      = (u16*)(ws + 234881024ull);         //  16,777,216
  int* offsFul = (int*)(ws + 251658240ull);         //   3,014,912
  int* esrcFul = (int*)(ws + 254673152ull);         //   5,898,240
  int* offsAll = (int*)(ws + 260571392ull);         //   2,097,408
  int* esrcAll = (int*)(ws + 262668800ull);         //   2,097,152
  u16* BT2_0   = (u16*)(ws + 264765952ull);         //   5 x 524,288
  u16* BT2_1   = BT2_0 + 262144;
  u16* BT2_2   = BT2_1 + 262144;
  u16* BT2_4   = BT2_2 + 262144;
  u16* BT2rt   = BT2_4 + 262144;
  u16* BT1op   = (u16*)(ws + 267387392ull);         //      65,536
  u16* BT1tab  = (u16*)(ws + 267452928ull);         //      65,536
  u16* BT1col  = (u16*)(ws + 267518464ull);         //     131,072
  u16* BT1pr   = (u16*)(ws + 267649536ull);         //      65,536
  float* b1op  = (float*)(ws + 267715072ull);       //   5 x 2048
  float* b1tab = b1op + 512, *b1col = b1op + 1024, *b1pr = b1op + 1536, *b2vec = b1op + 2048;
  float* pooled = (float*)(ws + 267725312ull);      //     131,072
  int* cnts     = (int*)(ws + 267856384ull);        //         256
  int* part     = (int*)(ws + 267856640ull);        //       4,096
  const size_t WS_NEED = 267860736ull;
  if (ws_size < WS_NEED) { probe_k<<<1, 64, 0, stream>>>(out, (float)ws_size); return; }

  // ---- A. CSR builds: full (7 rels) + filtered (rel2/rel4 x halves) ----
  hipMemsetAsync(curFul, 0, 3014912ull + 2097156ull, stream);
  EdgePtrs ep;
  for (int r = 0; r < 7; ++r) { ep.dst[r] = DST[r]; ep.src[r] = SRC[r]; }
  hist_multi<<<5760, 256, 0, stream>>>(ep, curFul);
  scan1_k<<<737, 256, 0, stream>>>(curFul, offsFul, part, TOT + 1);
  scan2_k<<<1, 1024, 0, stream>>>(part, 737);
  scan3_k<<<2945, 256, 0, stream>>>(offsFul, curFul, part, TOT + 1);
  fill_multi<<<5760, 256, 0, stream>>>(ep, curFul, esrcFul);
  FiltPtrs fpt;
  fpt.dst[0] = DST[2]; fpt.src[0] = SRC[2];
  fpt.dst[1] = DST[4]; fpt.src[1] = SRC[4];
  histf_multi<<<4096, 256, 0, stream>>>(fpt, curAll);
  scan1_k<<<513, 256, 0, stream>>>(curAll, offsAll, part, 524289);
  scan2_k<<<1, 1024, 0, stream>>>(part, 513);
  scan3_k<<<2049, 256, 0, stream>>>(offsAll, curAll, part, 524289);
  fillf_multi<<<4096, 256, 0, stream>>>(fpt, curAll, esrcAll);

  // ---- B. weight folding ----
  PackPtrs pp;
  pp.wl2 = Wl2; pp.wr2 = Wr2;
  pp.bt[0] = BT2_0; pp.bt[1] = BT2_1; pp.bt[2] = BT2_2; pp.bt[3] = BT2_4; pp.bt[4] = BT2rt;
  pack_multi<<<5120, 256, 0, stream>>>(pp);
  hipMemsetAsync(BT1op, 0, 65536 + 65536 + 131072 + 65536, stream);
  FoldPtrs fp;
  fp.a[0] = W_tab; fp.a[1] = b_tab; fp.a[2] = W_pred; fp.a[3] = b_pred;
  fp.a[4] = W_col; fp.a[5] = b_col; fp.a[6] = W_op;   fp.a[7] = b_op;
  fp.w[0] = Wl1;   fp.w[1] = Wr1;
  fp.bt[0] = BT1op; fp.bt[1] = BT1tab; fp.bt[2] = BT1col; fp.bt[3] = BT1pr;
  fold_multi<<<1256, 256, 0, stream>>>(fp);
  VFPtrs vp;
  vp.bl[0] = bl2; vp.bl[1] = bl1; vp.bl[2] = bl1; vp.bl[3] = bl1; vp.bl[4] = bl1;
  vp.bvec[0] = nullptr; vp.bvec[1] = b_op; vp.bvec[2] = b_tab; vp.bvec[3] = b_col; vp.bvec[4] = b_pred;
  vp.w = Wr1;
  vp.out[0] = b2vec; vp.out[1] = b1op; vp.out[2] = b1tab; vp.out[3] = b1col; vp.out[4] = b1pr;
  vecfold_multi<<<80, 256, 0, stream>>>(vp);

  // ---- D. relation 0: tab -> op (FIRST: initializes acc with layer-2 bias) ----
  hipMemsetAsync(A1, 0, 65536ull * 64 * 2, stream);  // covers D + E
  raw_agg<<<1024, 256, 0, stream>>>(offsFul + CSRB[5], esrcFul, x_tab, 2, A1, 64, 0, 2, 32768);
  a1_root<<<256, 256, 0, stream>>>(x_tab, 0, A1, 64, 3, 32768, 1);
  gemm_k<true, false, 64><<<dim3(256, 4), 256, 0, stream>>>(A1, BT1tab, b1tab, hsrc, 32768);
  ln_rows<<<8192, 256, 0, stream>>>(hsrc, g1, be1, 32768);
  fgemm_k<true><<<2048, 256, 0, stream>>>(offsFul + CSRB[0], offsFul + CSRB[0], esrcFul,
                                          hsrc, BT2_0, b2vec, acc);

  // ---- E. relation 1: pred -> op ----
  raw_agg<<<2048, 256, 0, stream>>>(offsFul + CSRB[3], esrcFul, x_col, 32, A1, 64, 0, 32, 65536);
  a1_root<<<1024, 256, 0, stream>>>(x_pred, 0, A1, 64, 33, 65536, 2);
  gemm_k<true, false, 64><<<dim3(512, 4), 256, 0, stream>>>(A1, BT1pr, b1pr, hsrc, 65536);
  ln_rows<<<16384, 256, 0, stream>>>(hsrc, g1, be1, 65536);
  fgemm_k<false><<<2048, 256, 0, stream>>>(offsFul + CSRB[1], offsFul + CSRB[1], esrcFul,
                                           hsrc, BT2_1, nullptr, acc);

  // ---- F. relation 2: col -> op (col recomputed in halves) ----
  hipMemsetAsync(A1, 0, 65536ull * 128 * 2, stream);
  for (int h = 0; h < 2; ++h) {
    int s0 = h * 65536;
    raw_agg<<<2048, 256, 0, stream>>>(offsFul + CSRB[6] + s0, esrcFul, x_col, 32, A1, 128, 0, 32, 65536);
    a1_root<<<8192, 256, 0, stream>>>(x_col, s0, A1, 128, 33, 65536, 5);
    gemm_k<true, false, 128><<<dim3(512, 4), 256, 0, stream>>>(A1, BT1col, b1col, hsrc, 65536);
    ln_rows<<<16384, 256, 0, stream>>>(hsrc, g1, be1, 65536);
    fgemm_k<false><<<2048, 256, 0, stream>>>(offsAll + h * 131072, offsFul + CSRB[2], esrcAll,
                                             hsrc, BT2_2, nullptr, acc);
  }

  // ---- G. op halves: root GEMM + relation 4 (op -> op) ----
  hipMemsetAsync(A1, 0, 65536ull * 64 * 2, stream);
  for (int h = 0; h < 2; ++h) {
    int s0 = h * 65536;
    RawPtrs rp;
    rp.offs = offsFul; rp.esrc = esrcFul; rp.A1 = A1;
    rp.x[0] = x_tab; rp.x[1] = x_pred; rp.x[2] = x_col; rp.x[3] = x_op;
    raw_multi<<<8192, 256, 0, stream>>>(rp, s0);
    a1_root<<<1024, 256, 0, stream>>>(x_op, s0, A1, 64, 46, 65536, 2);
    gemm_k<true, false, 64><<<dim3(512, 4), 256, 0, stream>>>(A1, BT1op, b1op, hsrc, 65536);
    ln_rows<<<16384, 256, 0, stream>>>(hsrc, g1, be1, 65536);
    gemm_k<false, true, 512><<<dim3(512, 4), 256, 0, stream>>>(hsrc, BT2rt, nullptr,
                                                               acc + (size_t)s0 * 512, 65536);
    fgemm_k<false><<<2048, 256, 0, stream>>>(offsAll + (2 + h) * 131072, offsFul + CSRB[4], esrcAll,
                                             hsrc, BT2_4, nullptr, acc);
  }

  // ---- H. fused ELU + LN2 + pool, then output ----
  hipMemsetAsync(pooled, 0, 64 * 512 * 4, stream);
  pool1v<<<1024, 256, 0, stream>>>(acc, batch, NOP, g2, be2, pooled, cnts);
  pool2<<<64, 64, 0, stream>>>(pooled, cnts, Wout, bout, out);
}

// Round 9
// 2276.440 us; speedup vs baseline: 1.1895x; 1.1895x over previous
//
#include <hip/hip_runtime.h>
#include <hip/hip_bf16.h>

typedef unsigned short u16;
typedef __attribute__((ext_vector_type(8))) short bf16x8;
typedef __attribute__((ext_vector_type(4))) short bf16x4;
typedef __attribute__((ext_vector_type(4))) float f32x4;

typedef __attribute__((address_space(1))) const void gv_t;  // global
typedef __attribute__((address_space(3))) void lv_t;        // LDS

#define DEVINL __device__ __forceinline__

DEVINL float bf2f(u16 s) { union { unsigned u; float f; } v; v.u = ((unsigned)s) << 16; return v.f; }
DEVINL u16 f2bf(float f) {
  union { float f; unsigned u; } v; v.f = f;
  return (u16)((v.u + 0x7FFFu + ((v.u >> 16) & 1u)) >> 16);
}

// ---- ws probe ----
__global__ void probe_k(float* __restrict__ out, float v) { out[threadIdx.x] = v; }

// ---- batched layer-2 packs: 5 jobs x 1024 blocks ----
struct PackPtrs { const float* wl2; const float* wr2; u16* bt[5]; };
__global__ __launch_bounds__(256) void pack_multi(PackPtrs p) {
  int j = blockIdx.x >> 10;
  int idx = (blockIdx.x & 1023) * 256 + threadIdx.x;
  int k = idx >> 9, n = idx & 511;
  float v;
  if (j < 4) {
    int r = (j == 3) ? 4 : j;
    v = p.wl2[((size_t)r * 512 + k) * 512 + n];
  } else {
    size_t o = (size_t)k * 512 + n;
    v = p.wr2[o] + p.wr2[o + 262144] + p.wr2[o + 524288] + p.wr2[o + 1048576];
  }
  p.bt[j][(size_t)n * 512 + k] = f2bf(v * 0.25f);
}

// ================= batched layer-1 weight folding (18 jobs) =================
struct FoldPtrs { const float* a[8]; const float* w[2]; u16* bt[4]; };
__constant__ int   c_off[19] = {0,16,24,56,64,320,328,360,368,400,416,424,440,696,704,960,1216,1224,1256};
__constant__ int   c_ai[18]  = {0,1,2,3,4,5,6,7,6, 0,1,0, 4,5,4, 4,5,2};
__constant__ int   c_wi[18]  = {0,0,0,0,0,0,0,0,1, 0,0,1, 0,0,1, 0,0,1};
__constant__ int   c_r0[18]  = {0,0,1,1,2,2,4,4,0, 5,5,5, 6,6,6, 3,3,3};
__constant__ float c_sc[18]  = {0.25f,0.25f,0.25f,0.25f,0.25f,0.25f,0.25f,0.25f,0.25f,
                                1.f,1.f,1.f, 1.f,1.f,1.f, 1.f,1.f,1.f};
__constant__ int   c_bt[18]  = {0,0,0,0,0,0,0,0,0, 1,1,1, 2,2,2, 3,3,3};
__constant__ int   c_K[18]   = {64,64,64,64,64,64,64,64,64, 64,64,64, 128,128,128, 64,64,64};
__constant__ int   c_ko[18]  = {0,2,3,7,8,40,41,45,46, 0,2,3, 0,32,33, 0,32,33};

__global__ __launch_bounds__(256) void fold_multi(FoldPtrs p) {
  __shared__ float red[256];
  int b = blockIdx.x;
  int j = 0;
#pragma unroll
  for (int t = 1; t < 18; ++t) j += (b >= c_off[t]);
  int rel = b - c_off[j];
  int f = rel >> 3, nb = rel & 7;
  int tid = threadIdx.x;
  int n = nb * 64 + (tid & 63);
  int kg = tid >> 6;
  const float* A = p.a[c_ai[j]] + (size_t)f * 512;
  const float* W = p.w[c_wi[j]];
  int k0 = kg * 128;
  float acc = 0.f;
  if (j != 8) {
    const float* Wp = W + (size_t)c_r0[j] * 512 * 512 + n;
#pragma unroll 16
    for (int k = k0; k < k0 + 128; ++k) acc += A[k] * Wp[(size_t)k * 512];
  } else {
    const float* W0 = W + n;
    const float* W1 = W + (size_t)262144 + n;
    const float* W2 = W + (size_t)524288 + n;
    const float* W4 = W + (size_t)1048576 + n;
#pragma unroll 8
    for (int k = k0; k < k0 + 128; ++k) {
      size_t o = (size_t)k * 512;
      acc += A[k] * (W0[o] + W1[o] + W2[o] + W4[o]);
    }
  }
  red[tid] = acc;
  __syncthreads();
  if (kg == 0) {
    float v = red[tid] + red[tid + 64] + red[tid + 128] + red[tid + 192];
    p.bt[c_bt[j]][(size_t)n * c_K[j] + c_ko[j] + f] = f2bf(v * c_sc[j]);
  }
}

// ---- batched bias folds ----
struct VFPtrs { const float* bl[5]; const float* bvec[5]; const float* w; float* out[5]; };
__constant__ int   c_vi[5][4] = {{0,1,2,4},{0,1,2,4},{5,-1,-1,-1},{6,-1,-1,-1},{3,-1,-1,-1}};
__constant__ float c_vs[5]    = {0.25f,0.25f,1.f,1.f,1.f};

__global__ __launch_bounds__(256) void vecfold_multi(VFPtrs p) {
  __shared__ float red[256];
  int j = blockIdx.x >> 4, blk = blockIdx.x & 15;
  int tid = threadIdx.x;
  int n = blk * 32 + (tid & 31);
  int kg = tid >> 5;
  const float* bv = p.bvec[j];
  float a = 0.f;
  if (bv) {
    int i1 = c_vi[j][1];
    const float* W0 = p.w + (size_t)c_vi[j][0] * 262144 + n;
    if (i1 < 0) {
#pragma unroll 16
      for (int k = kg * 64; k < kg * 64 + 64; ++k) a += bv[k] * W0[(size_t)k * 512];
    } else {
      const float* W1 = p.w + (size_t)c_vi[j][1] * 262144 + n;
      const float* W2 = p.w + (size_t)c_vi[j][2] * 262144 + n;
      const float* W3 = p.w + (size_t)c_vi[j][3] * 262144 + n;
#pragma unroll 8
      for (int k = kg * 64; k < kg * 64 + 64; ++k) {
        size_t o = (size_t)k * 512;
        a += bv[k] * (W0[o] + W1[o] + W2[o] + W3[o]);
      }
    }
  }
  red[tid] = a;
  __syncthreads();
  if (kg == 0) {
    float v = 0.f;
#pragma unroll
    for (int q = 0; q < 8; ++q) v += red[(tid & 31) + q * 32];
    float bsum = p.bl[j][c_vi[j][0] * 512 + n];
    if (c_vi[j][1] >= 0) {
      bsum += p.bl[j][c_vi[j][1] * 512 + n];
      bsum += p.bl[j][c_vi[j][2] * 512 + n];
      bsum += p.bl[j][c_vi[j][3] * 512 + n];
    }
    p.out[j][n] = (v + bsum) * c_vs[j];
  }
}

// ================= CSR build (batched) =================
struct EdgePtrs { const int* dst[7]; const int* src[7]; };
__constant__ int c_hoff[8]  = {0,1024,2048,3072,4096,5120,5248,5760};
__constant__ int c_hbase[7] = {0,131072,262144,393216,458752,589824,622592};
__constant__ int c_hne[7]   = {262144,262144,262144,262144,262144,32768,131072};

__global__ __launch_bounds__(256) void hist_multi(EdgePtrs p, int* __restrict__ cnt) {
  int b = blockIdx.x;
  int j = 0;
#pragma unroll
  for (int t = 1; t < 7; ++t) j += (b >= c_hoff[t]);
  int i = (b - c_hoff[j]) * 256 + threadIdx.x;
  if (i < c_hne[j]) atomicAdd(&cnt[c_hbase[j] + p.dst[j][i]], 1);
}

__global__ __launch_bounds__(256) void fill_multi(EdgePtrs p, int* __restrict__ cursor,
                                                  int* __restrict__ esrc) {
  int b = blockIdx.x;
  int j = 0;
#pragma unroll
  for (int t = 1; t < 7; ++t) j += (b >= c_hoff[t]);
  int i = (b - c_hoff[j]) * 256 + threadIdx.x;
  if (i < c_hne[j]) {
    int pos = atomicAdd(&cursor[c_hbase[j] + p.dst[j][i]], 1);
    esrc[pos] = p.src[j][i];
  }
}

// filtered CSRs: 4 jobs (rel2 h0, rel2 h1, rel4 h0, rel4 h1), 1024 blocks each
struct FiltPtrs { const int* dst[2]; const int* src[2]; };
__global__ __launch_bounds__(256) void histf_multi(FiltPtrs p, int* __restrict__ cnt) {
  int j = blockIdx.x >> 10;
  int rel = j >> 1, s0 = (j & 1) * 65536;
  int i = (blockIdx.x & 1023) * 256 + threadIdx.x;
  int s = p.src[rel][i];
  if (s >= s0 && s < s0 + 65536) atomicAdd(&cnt[j * 131072 + p.dst[rel][i]], 1);
}
__global__ __launch_bounds__(256) void fillf_multi(FiltPtrs p, int* __restrict__ cursor,
                                                   int* __restrict__ esrc) {
  int j = blockIdx.x >> 10;
  int rel = j >> 1, s0 = (j & 1) * 65536;
  int i = (blockIdx.x & 1023) * 256 + threadIdx.x;
  int s = p.src[rel][i];
  if (s >= s0 && s < s0 + 65536) {
    int pos = atomicAdd(&cursor[j * 131072 + p.dst[rel][i]], 1);
    esrc[pos] = s - s0;
  }
}

__global__ void scan1_k(const int* __restrict__ in, int* __restrict__ out,
                        int* __restrict__ part, int n) {
  __shared__ int s[256];
  int t = threadIdx.x;
  int base = blockIdx.x * 1024 + t * 4;
  int x0 = 0, x1 = 0, x2 = 0, x3 = 0;
  if (base < n) x0 = in[base];
  if (base + 1 < n) x1 = in[base + 1];
  if (base + 2 < n) x2 = in[base + 2];
  if (base + 3 < n) x3 = in[base + 3];
  int tsum = x0 + x1 + x2 + x3;
  s[t] = tsum;
  __syncthreads();
  for (int off = 1; off < 256; off <<= 1) {
    int v = (t >= off) ? s[t - off] : 0;
    __syncthreads();
    s[t] += v;
    __syncthreads();
  }
  int excl = s[t] - tsum;
  if (base < n) out[base] = excl;
  if (base + 1 < n) out[base + 1] = excl + x0;
  if (base + 2 < n) out[base + 2] = excl + x0 + x1;
  if (base + 3 < n) out[base + 3] = excl + x0 + x1 + x2;
  if (t == 255) part[blockIdx.x] = s[255];
}

__global__ void scan2_k(int* __restrict__ part, int nb) {
  __shared__ int s[1024];
  int t = threadIdx.x;
  int orig = (t < nb) ? part[t] : 0;
  s[t] = orig;
  __syncthreads();
  for (int off = 1; off < 1024; off <<= 1) {
    int v = (t >= off) ? s[t - off] : 0;
    __syncthreads();
    s[t] += v;
    __syncthreads();
  }
  if (t < nb) part[t] = s[t] - orig;
}

__global__ void scan3_k(int* __restrict__ out, int* __restrict__ cursor,
                        const int* __restrict__ part, int n) {
  int i = blockIdx.x * 256 + threadIdx.x;
  if (i < n) {
    int v = out[i] + part[i >> 10];
    out[i] = v;
    cursor[i] = v;
  }
}

// ---- raw-feature segment mean + indicator (8 threads per dst row) ----
__global__ void raw_agg(const int* __restrict__ offs, const int* __restrict__ esrc,
                        const float* __restrict__ x, int F, u16* __restrict__ A1,
                        int K, int colOff, int indCol, int nd) {
  int row = blockIdx.x * 32 + (threadIdx.x >> 3);
  if (row >= nd) return;
  int j = threadIdx.x & 7;
  int e0 = offs[row], e1 = offs[row + 1];
  float acc[4] = {0.f, 0.f, 0.f, 0.f};
  for (int e = e0; e < e1; ++e) {
    int s = esrc[e];
#pragma unroll
    for (int u = 0; u < 4; ++u) {
      int f = j + u * 8;
      if (f < F) acc[u] += x[(size_t)s * F + f];
    }
  }
  float inv = (e1 > e0) ? 1.f / (float)(e1 - e0) : 0.f;
#pragma unroll
  for (int u = 0; u < 4; ++u) {
    int f = j + u * 8;
    if (f < F) A1[(size_t)row * K + colOff + f] = f2bf(acc[u] * inv);
  }
  if (j == 0) A1[(size_t)row * K + indCol] = f2bf((e1 > e0) ? 1.f : 0.f);
}

// batched version for stage G: 4 jobs x 2048 blocks, K=64, nd=65536
struct RawPtrs { const int* offs; const int* esrc; const float* x[4]; u16* A1; };
__constant__ int c_gF[4]    = {2,4,32,4};
__constant__ int c_gco[4]   = {0,3,8,41};
__constant__ int c_gic[4]   = {2,7,40,45};
__constant__ int c_gcsrb[4] = {0,131072,262144,458752};

__global__ __launch_bounds__(256) void raw_multi(RawPtrs p, int s0) {
  int j = blockIdx.x >> 11;
  int row = (blockIdx.x & 2047) * 32 + (threadIdx.x >> 3);
  int jj = threadIdx.x & 7;
  const int* offs = p.offs + c_gcsrb[j] + s0;
  const float* x = p.x[j];
  int F = c_gF[j];
  int e0 = offs[row], e1 = offs[row + 1];
  float acc[4] = {0.f, 0.f, 0.f, 0.f};
  for (int e = e0; e < e1; ++e) {
    int s = p.esrc[e];
#pragma unroll
    for (int u = 0; u < 4; ++u) {
      int f = jj + u * 8;
      if (f < F) acc[u] += x[(size_t)s * F + f];
    }
  }
  float inv = (e1 > e0) ? 1.f / (float)(e1 - e0) : 0.f;
#pragma unroll
  for (int u = 0; u < 4; ++u) {
    int f = jj + u * 8;
    if (f < F) p.A1[(size_t)row * 64 + c_gco[j] + f] = f2bf(acc[u] * inv);
  }
  if (jj == 0) p.A1[(size_t)row * 64 + c_gic[j]] = f2bf((e1 > e0) ? 1.f : 0.f);
}

// ---- copy root raw features into A1 ----
__global__ void a1_root(const float* __restrict__ x, int rowBase, u16* __restrict__ A1,
                        int K, int rootOff, int nd, int lf) {
  int idx = blockIdx.x * 256 + threadIdx.x;
  int i = idx >> lf, f = idx & ((1 << lf) - 1);
  if (i >= nd) return;
  A1[(size_t)i * K + rootOff + f] = f2bf(x[(((size_t)(rowBase + i)) << lf) + f]);
}

// ---- gather partial segment-sums scaled by 1/full-count (wave per dst row) ----
__global__ void seg_gather2(const int* __restrict__ offsF, const int* __restrict__ offsS,
                            const int* __restrict__ esrcF, const u16* __restrict__ hsrc,
                            u16* __restrict__ agg, int nd) {
  int w = blockIdx.x * 4 + (threadIdx.x >> 6);
  if (w >= nd) return;
  int l = threadIdx.x & 63;
  int e0 = offsF[w], e1 = offsF[w + 1];
  int c0 = offsS[w], c1 = offsS[w + 1];
  float inv = (c1 > c0) ? 1.f / (float)(c1 - c0) : 0.f;
  float acc[8] = {0.f, 0.f, 0.f, 0.f, 0.f, 0.f, 0.f, 0.f};
  for (int e = e0; e < e1; ++e) {
    int s = esrcF[e];
    bf16x8 v = *(const bf16x8*)&hsrc[(size_t)s * 512 + l * 8];
#pragma unroll
    for (int j = 0; j < 8; ++j) acc[j] += bf2f((u16)v[j]);
  }
  bf16x8 r;
#pragma unroll
  for (int j = 0; j < 8; ++j) r[j] = (short)f2bf(acc[j] * inv);
  *(bf16x8*)&agg[(size_t)w * 512 + l * 8] = r;
}

// ---- MFMA GEMM: C[M][512] (+)= op(A[M][K] @ BT[512][K]^T + bias), bf16 ----
// Swapped-operand MFMA: lane owns 4 consecutive C columns -> 8-B vector RMW epilogue.
template <bool ELU, bool ACC, int K>
__global__ __launch_bounds__(256) void gemm_k(
    const u16* __restrict__ A, const u16* __restrict__ BT,
    const float* __restrict__ bias, u16* __restrict__ C, int M) {
  __shared__ u16 As[128 * 64];
  __shared__ u16 Bs[128 * 64];
  int tid = threadIdx.x;
  int wid = tid >> 6, lane = tid & 63;
  int wm = wid >> 1, wn = wid & 1;
  int bm = blockIdx.x * 128, bn = blockIdx.y * 128;
  int r16 = lane & 15, hi4 = lane >> 4;
  int srow = tid >> 3;
  int scol = ((tid & 7) ^ (srow & 7)) * 8;  // pre-swizzled source column group
  int sw = r16 & 7;                          // read-side XOR key
  f32x4 acc[4][4];
#pragma unroll
  for (int i = 0; i < 4; ++i)
#pragma unroll
    for (int j = 0; j < 4; ++j) acc[i][j] = (f32x4){0.f, 0.f, 0.f, 0.f};

#pragma unroll
  for (int k0 = 0; k0 < K; k0 += 64) {
    __syncthreads();
#pragma unroll
    for (int i = 0; i < 4; ++i) {
      const u16* ga = A + (size_t)(bm + i * 32 + srow) * K + k0 + scol;
      const u16* gb = BT + (size_t)(bn + i * 32 + srow) * K + k0 + scol;
      __builtin_amdgcn_global_load_lds((gv_t*)ga, (lv_t*)(As + i * 2048 + wid * 512), 16, 0, 0);
      __builtin_amdgcn_global_load_lds((gv_t*)gb, (lv_t*)(Bs + i * 2048 + wid * 512), 16, 0, 0);
    }
    __syncthreads();
#pragma unroll
    for (int kk = 0; kk < 64; kk += 32) {
      bf16x8 af[4], bfr[4];
#pragma unroll
      for (int f = 0; f < 4; ++f) {
        int grp = (kk >> 3) + hi4;
        af[f]  = *(const bf16x8*)&As[(wm * 64 + f * 16 + r16) * 64 + ((grp ^ sw) << 3)];
        bfr[f] = *(const bf16x8*)&Bs[(wn * 64 + f * 16 + r16) * 64 + ((grp ^ sw) << 3)];
      }
      // swapped operands: lane -> C row via r16, 4 consecutive C cols via hi4*4+j
#pragma unroll
      for (int mf = 0; mf < 4; ++mf)
#pragma unroll
        for (int nf = 0; nf < 4; ++nf)
          acc[mf][nf] = __builtin_amdgcn_mfma_f32_16x16x32_bf16(bfr[nf], af[mf], acc[mf][nf], 0, 0, 0);
    }
  }
  // epilogue: vectorized 8-B RMW per fragment
#pragma unroll
  for (int mf = 0; mf < 4; ++mf) {
    int r = bm + wm * 64 + mf * 16 + r16;
#pragma unroll
    for (int nf = 0; nf < 4; ++nf) {
      int c0 = bn + wn * 64 + nf * 16 + hi4 * 4;
      u16* cp = C + (size_t)r * 512 + c0;
      bf16x4 oldv;
      if (ACC) oldv = *(const bf16x4*)cp;
      f32x4 bv;
      if (bias) bv = *(const f32x4*)&bias[c0];
      bf16x4 res;
#pragma unroll
      for (int j = 0; j < 4; ++j) {
        float v = acc[mf][nf][j] + (bias ? bv[j] : 0.f);
        if (ACC) v += bf2f((u16)oldv[j]);
        if (ELU) v = v > 0.f ? v : expm1f(v);
        res[j] = (short)f2bf(v);
      }
      *(bf16x4*)cp = res;
    }
  }
}

// ---- LayerNorm in place (wave per row) ----
__global__ void ln_rows(u16* __restrict__ H, const float* __restrict__ g,
                        const float* __restrict__ be, int rows) {
  int w = blockIdx.x * 4 + (threadIdx.x >> 6);
  if (w >= rows) return;
  int l = threadIdx.x & 63;
  u16* p = H + (size_t)w * 512 + l * 8;
  bf16x8 v = *(const bf16x8*)p;
  float x[8];
  float s = 0.f;
#pragma unroll
  for (int j = 0; j < 8; ++j) { x[j] = bf2f((u16)v[j]); s += x[j]; }
#pragma unroll
  for (int m = 1; m < 64; m <<= 1) s += __shfl_xor(s, m, 64);
  float mean = s * (1.f / 512.f);
  float q = 0.f;
#pragma unroll
  for (int j = 0; j < 8; ++j) { float d = x[j] - mean; q += d * d; }
#pragma unroll
  for (int m = 1; m < 64; m <<= 1) q += __shfl_xor(q, m, 64);
  float rsd = rsqrtf(q * (1.f / 512.f) + 1e-5f);
  bf16x8 r;
#pragma unroll
  for (int j = 0; j < 8; ++j) {
    int c = l * 8 + j;
    r[j] = (short)f2bf((x[j] - mean) * rsd * g[c] + be[c]);
  }
  *(bf16x8*)p = r;
}

// ---- fused ELU + LN2 + pool partial-sum ----
DEVINL int lowb(const int* a, int n, int v) {
  int lo = 0, hi = n;
  while (lo < hi) { int m = (lo + hi) >> 1; if (a[m] < v) lo = m + 1; else hi = m; }
  return lo;
}

__global__ __launch_bounds__(256) void pool1v(const u16* __restrict__ H,
                                              const int* __restrict__ batch, int nOp,
                                              const float* __restrict__ g2,
                                              const float* __restrict__ be2,
                                              float* __restrict__ pooled,
                                              int* __restrict__ cnts) {
  __shared__ float red[4][512];
  int gr = blockIdx.x >> 4, part = blockIdx.x & 15;
  int lo = lowb(batch, nOp, gr), hi = lowb(batch, nOp, gr + 1);
  if (part == 0 && threadIdx.x == 0) cnts[gr] = hi - lo;
  int len = hi - lo;
  int chunk = (len + 15) >> 4;
  int r0 = lo + part * chunk;
  int r1 = r0 + chunk;
  if (r1 > hi) r1 = hi;
  int wv = threadIdx.x >> 6, l = threadIdx.x & 63;
  float a[8] = {0.f, 0.f, 0.f, 0.f, 0.f, 0.f, 0.f, 0.f};
  float gv[8], bv[8];
#pragma unroll
  for (int j = 0; j < 8; ++j) { gv[j] = g2[l * 8 + j]; bv[j] = be2[l * 8 + j]; }
  for (int r = r0 + wv; r < r1; r += 4) {
    bf16x8 v = *(const bf16x8*)&H[(size_t)r * 512 + l * 8];
    float x[8];
    float s = 0.f;
#pragma unroll
    for (int j = 0; j < 8; ++j) {
      x[j] = bf2f((u16)v[j]);
      x[j] = x[j] > 0.f ? x[j] : expm1f(x[j]);
      s += x[j];
    }
#pragma unroll
    for (int m = 1; m < 64; m <<= 1) s += __shfl_xor(s, m, 64);
    float mean = s * (1.f / 512.f);
    float q = 0.f;
#pragma unroll
    for (int j = 0; j < 8; ++j) { float d = x[j] - mean; q += d * d; }
#pragma unroll
    for (int m = 1; m < 64; m <<= 1) q += __shfl_xor(q, m, 64);
    float rsd = rsqrtf(q * (1.f / 512.f) + 1e-5f);
#pragma unroll
    for (int j = 0; j < 8; ++j) a[j] += (x[j] - mean) * rsd * gv[j] + bv[j];
  }
#pragma unroll
  for (int j = 0; j < 8; ++j) red[wv][l * 8 + j] = a[j];
  __syncthreads();
  if (wv == 0) {
#pragma unroll
    for (int j = 0; j < 8; ++j) {
      int c = l * 8 + j;
      float s = red[0][c] + red[1][c] + red[2][c] + red[3][c];
      atomicAdd(&pooled[gr * 512 + c], s);
    }
  }
}

__global__ void pool2(const float* __restrict__ pooled, const int* __restrict__ cnts,
                      const float* __restrict__ Wout, const float* __restrict__ bout,
                      float* __restrict__ out) {
  int gg = blockIdx.x;
  int l = threadIdx.x;
  float s = 0.f;
#pragma unroll
  for (int j = 0; j < 8; ++j) {
    int c = l * 8 + j;
    s += pooled[gg * 512 + c] * Wout[c];
  }
#pragma unroll
  for (int m = 1; m < 64; m <<= 1) s += __shfl_xor(s, m, 64);
  if (l == 0) {
    int c = cnts[gg];
    if (c < 1) c = 1;
    out[gg] = s / (float)c + bout[0];
  }
}

extern "C" void kernel_launch(void* const* d_in, const int* in_sizes, int n_in,
                              void* d_out, int out_size, void* d_ws, size_t ws_size,
                              hipStream_t stream) {
  (void)in_sizes; (void)n_in; (void)out_size;
  const float* x_op   = (const float*)d_in[0];
  const float* x_tab  = (const float*)d_in[1];
  const float* x_col  = (const float*)d_in[2];
  const float* x_pred = (const float*)d_in[3];
  const float* W_op = (const float*)d_in[4],  *b_op = (const float*)d_in[5];
  const float* W_tab = (const float*)d_in[6], *b_tab = (const float*)d_in[7];
  const float* W_col = (const float*)d_in[8], *b_col = (const float*)d_in[9];
  const float* W_pred = (const float*)d_in[10], *b_pred = (const float*)d_in[11];
  const float* Wl1 = (const float*)d_in[12];
  const float* bl1 = (const float*)d_in[13];
  const float* Wr1 = (const float*)d_in[14];
  const float* Wl2 = (const float*)d_in[15];
  const float* bl2 = (const float*)d_in[16];
  const float* Wr2 = (const float*)d_in[17];
  const float* g1  = (const float*)d_in[18];
  const float* be1 = (const float*)d_in[19];
  const float* g2  = (const float*)d_in[20];
  const float* be2 = (const float*)d_in[21];
  const float* Wout = (const float*)d_in[22];
  const float* bout = (const float*)d_in[23];
  const int* SRC[7], *DST[7];
  for (int r = 0; r < 7; ++r) { SRC[r] = (const int*)d_in[24 + 2 * r]; DST[r] = (const int*)d_in[25 + 2 * r]; }
  const int* batch = (const int*)d_in[38];
  float* out = (float*)d_out;

  const int CSRB[7] = {0, 131072, 262144, 393216, 458752, 589824, 622592};
  const int TOT = 753664;
  const int NOP = 131072;

  // ---- workspace layout (256 MiB) ----
  char* ws = (char*)d_ws;
  u16* acc     = (u16*)ws;                          // 134,217,728
  u16* hsrc    = (u16*)(ws + 134217728ull);         //  67,108,864
  u16* agg     = (u16*)(ws + 201326592ull);         //  33,554,432 (CSR cursors overlay)
  int* curFul  = (int*)(ws + 201326592ull);
  int* curAll  = (int*)(ws + 204341504ull);
  u16* A1      = (u16*)(ws + 234881024ull);         //  16,777,216
  int* offsFul = (int*)(ws + 251658240ull);         //   3,014,912
  int* esrcFul = (int*)(ws + 254673152ull);         //   5,898,240
  int* offsAll = (int*)(ws + 260571392ull);         //   2,097,408
  int* esrcAll = (int*)(ws + 262668800ull);         //   2,097,152
  u16* BT2_0   = (u16*)(ws + 264765952ull);         //   5 x 524,288
  u16* BT2_1   = BT2_0 + 262144;
  u16* BT2_2   = BT2_1 + 262144;
  u16* BT2_4   = BT2_2 + 262144;
  u16* BT2rt   = BT2_4 + 262144;
  u16* BT1op   = (u16*)(ws + 267387392ull);         //      65,536
  u16* BT1tab  = (u16*)(ws + 267452928ull);         //      65,536
  u16* BT1col  = (u16*)(ws + 267518464ull);         //     131,072
  u16* BT1pr   = (u16*)(ws + 267649536ull);         //      65,536
  float* b1op  = (float*)(ws + 267715072ull);       //   5 x 2048
  float* b1tab = b1op + 512, *b1col = b1op + 1024, *b1pr = b1op + 1536, *b2vec = b1op + 2048;
  float* pooled = (float*)(ws + 267725312ull);      //     131,072
  int* cnts     = (int*)(ws + 267856384ull);        //         256
  int* part     = (int*)(ws + 267856640ull);        //       4,096
  const size_t WS_NEED = 267860736ull;
  if (ws_size < WS_NEED) { probe_k<<<1, 64, 0, stream>>>(out, (float)ws_size); return; }

  // ---- A. CSR builds: full (7 rels) + filtered (rel2/rel4 x halves) ----
  (void)hipMemsetAsync(curFul, 0, 3014912ull + 2097156ull, stream);
  EdgePtrs ep;
  for (int r = 0; r < 7; ++r) { ep.dst[r] = DST[r]; ep.src[r] = SRC[r]; }
  hist_multi<<<5760, 256, 0, stream>>>(ep, curFul);
  scan1_k<<<737, 256, 0, stream>>>(curFul, offsFul, part, TOT + 1);
  scan2_k<<<1, 1024, 0, stream>>>(part, 737);
  scan3_k<<<2945, 256, 0, stream>>>(offsFul, curFul, part, TOT + 1);
  fill_multi<<<5760, 256, 0, stream>>>(ep, curFul, esrcFul);
  FiltPtrs fpt;
  fpt.dst[0] = DST[2]; fpt.src[0] = SRC[2];
  fpt.dst[1] = DST[4]; fpt.src[1] = SRC[4];
  histf_multi<<<4096, 256, 0, stream>>>(fpt, curAll);
  scan1_k<<<513, 256, 0, stream>>>(curAll, offsAll, part, 524289);
  scan2_k<<<1, 1024, 0, stream>>>(part, 513);
  scan3_k<<<2049, 256, 0, stream>>>(offsAll, curAll, part, 524289);
  fillf_multi<<<4096, 256, 0, stream>>>(fpt, curAll, esrcAll);

  // ---- B. weight folding ----
  PackPtrs pp;
  pp.wl2 = Wl2; pp.wr2 = Wr2;
  pp.bt[0] = BT2_0; pp.bt[1] = BT2_1; pp.bt[2] = BT2_2; pp.bt[3] = BT2_4; pp.bt[4] = BT2rt;
  pack_multi<<<5120, 256, 0, stream>>>(pp);
  (void)hipMemsetAsync(BT1op, 0, 65536 + 65536 + 131072 + 65536, stream);
  FoldPtrs fp;
  fp.a[0] = W_tab; fp.a[1] = b_tab; fp.a[2] = W_pred; fp.a[3] = b_pred;
  fp.a[4] = W_col; fp.a[5] = b_col; fp.a[6] = W_op;   fp.a[7] = b_op;
  fp.w[0] = Wl1;   fp.w[1] = Wr1;
  fp.bt[0] = BT1op; fp.bt[1] = BT1tab; fp.bt[2] = BT1col; fp.bt[3] = BT1pr;
  fold_multi<<<1256, 256, 0, stream>>>(fp);
  VFPtrs vp;
  vp.bl[0] = bl2; vp.bl[1] = bl1; vp.bl[2] = bl1; vp.bl[3] = bl1; vp.bl[4] = bl1;
  vp.bvec[0] = nullptr; vp.bvec[1] = b_op; vp.bvec[2] = b_tab; vp.bvec[3] = b_col; vp.bvec[4] = b_pred;
  vp.w = Wr1;
  vp.out[0] = b2vec; vp.out[1] = b1op; vp.out[2] = b1tab; vp.out[3] = b1col; vp.out[4] = b1pr;
  vecfold_multi<<<80, 256, 0, stream>>>(vp);

  // helper: 4x agg-chunk + accumulate-GEMM over all op dst rows
  auto rel_pass = [&](const int* oF, const int* oS, const int* eF, const u16* bt, bool first) {
    for (int c = 0; c < 4; ++c) {
      int c0 = c * 32768;
      seg_gather2<<<8192, 256, 0, stream>>>(oF + c0, oS + c0, eF, hsrc, agg, 32768);
      if (first)
        gemm_k<false, false, 512><<<dim3(256, 4), 256, 0, stream>>>(agg, bt, b2vec,
                                                                    acc + (size_t)c0 * 512, 32768);
      else
        gemm_k<false, true, 512><<<dim3(256, 4), 256, 0, stream>>>(agg, bt, nullptr,
                                                                   acc + (size_t)c0 * 512, 32768);
    }
  };

  // ---- D. relation 0: tab -> op (FIRST: initializes acc with layer-2 bias) ----
  (void)hipMemsetAsync(A1, 0, 65536ull * 64 * 2, stream);  // covers D + E
  raw_agg<<<1024, 256, 0, stream>>>(offsFul + CSRB[5], esrcFul, x_tab, 2, A1, 64, 0, 2, 32768);
  a1_root<<<256, 256, 0, stream>>>(x_tab, 0, A1, 64, 3, 32768, 1);
  gemm_k<true, false, 64><<<dim3(256, 4), 256, 0, stream>>>(A1, BT1tab, b1tab, hsrc, 32768);
  ln_rows<<<8192, 256, 0, stream>>>(hsrc, g1, be1, 32768);
  rel_pass(offsFul + CSRB[0], offsFul + CSRB[0], esrcFul, BT2_0, true);

  // ---- E. relation 1: pred -> op ----
  raw_agg<<<2048, 256, 0, stream>>>(offsFul + CSRB[3], esrcFul, x_col, 32, A1, 64, 0, 32, 65536);
  a1_root<<<1024, 256, 0, stream>>>(x_pred, 0, A1, 64, 33, 65536, 2);
  gemm_k<true, false, 64><<<dim3(512, 4), 256, 0, stream>>>(A1, BT1pr, b1pr, hsrc, 65536);
  ln_rows<<<16384, 256, 0, stream>>>(hsrc, g1, be1, 65536);
  rel_pass(offsFul + CSRB[1], offsFul + CSRB[1], esrcFul, BT2_1, false);

  // ---- F. relation 2: col -> op (col recomputed in halves) ----
  (void)hipMemsetAsync(A1, 0, 65536ull * 128 * 2, stream);
  for (int h = 0; h < 2; ++h) {
    int s0 = h * 65536;
    raw_agg<<<2048, 256, 0, stream>>>(offsFul + CSRB[6] + s0, esrcFul, x_col, 32, A1, 128, 0, 32, 65536);
    a1_root<<<8192, 256, 0, stream>>>(x_col, s0, A1, 128, 33, 65536, 5);
    gemm_k<true, false, 128><<<dim3(512, 4), 256, 0, stream>>>(A1, BT1col, b1col, hsrc, 65536);
    ln_rows<<<16384, 256, 0, stream>>>(hsrc, g1, be1, 65536);
    rel_pass(offsAll + h * 131072, offsFul + CSRB[2], esrcAll, BT2_2, false);
  }

  // ---- G. op halves: root GEMM + relation 4 (op -> op) ----
  (void)hipMemsetAsync(A1, 0, 65536ull * 64 * 2, stream);
  for (int h = 0; h < 2; ++h) {
    int s0 = h * 65536;
    RawPtrs rp;
    rp.offs = offsFul; rp.esrc = esrcFul; rp.A1 = A1;
    rp.x[0] = x_tab; rp.x[1] = x_pred; rp.x[2] = x_col; rp.x[3] = x_op;
    raw_multi<<<8192, 256, 0, stream>>>(rp, s0);
    a1_root<<<1024, 256, 0, stream>>>(x_op, s0, A1, 64, 46, 65536, 2);
    gemm_k<true, false, 64><<<dim3(512, 4), 256, 0, stream>>>(A1, BT1op, b1op, hsrc, 65536);
    ln_rows<<<16384, 256, 0, stream>>>(hsrc, g1, be1, 65536);
    gemm_k<false, true, 512><<<dim3(512, 4), 256, 0, stream>>>(hsrc, BT2rt, nullptr,
                                                               acc + (size_t)s0 * 512, 65536);
    rel_pass(offsAll + (2 + h) * 131072, offsFul + CSRB[4], esrcAll, BT2_4, false);
  }

  // ---- H. fused ELU + LN2 + pool, then output ----
  (void)hipMemsetAsync(pooled, 0, 64 * 512 * 4, stream);
  pool1v<<<1024, 256, 0, stream>>>(acc, batch, NOP, g2, be2, pooled, cnts);
  pool2<<<64, 64, 0, stream>>>(pooled, cnts, Wout, bout, out);
}

// Round 10
// 1698.383 us; speedup vs baseline: 1.5943x; 1.3404x over previous
//
#include <hip/hip_runtime.h>
#include <hip/hip_bf16.h>

typedef unsigned short u16;
typedef __attribute__((ext_vector_type(8))) short bf16x8;
typedef __attribute__((ext_vector_type(4))) short bf16x4;
typedef __attribute__((ext_vector_type(4))) float f32x4;

typedef __attribute__((address_space(1))) const void gv_t;  // global
typedef __attribute__((address_space(3))) void lv_t;        // LDS

#define DEVINL __device__ __forceinline__

DEVINL float bf2f(u16 s) { union { unsigned u; float f; } v; v.u = ((unsigned)s) << 16; return v.f; }
DEVINL u16 f2bf(float f) {
  union { float f; unsigned u; } v; v.f = f;
  return (u16)((v.u + 0x7FFFu + ((v.u >> 16) & 1u)) >> 16);
}

// ---- ws probe ----
__global__ void probe_k(float* __restrict__ out, float v) { out[threadIdx.x] = v; }

// ---- batched layer-2 packs: 5 jobs x 1024 blocks ----
struct PackPtrs { const float* wl2; const float* wr2; u16* bt[5]; };
__global__ __launch_bounds__(256) void pack_multi(PackPtrs p) {
  int j = blockIdx.x >> 10;
  int idx = (blockIdx.x & 1023) * 256 + threadIdx.x;
  int k = idx >> 9, n = idx & 511;
  float v;
  if (j < 4) {
    int r = (j == 3) ? 4 : j;
    v = p.wl2[((size_t)r * 512 + k) * 512 + n];
  } else {
    size_t o = (size_t)k * 512 + n;
    v = p.wr2[o] + p.wr2[o + 262144] + p.wr2[o + 524288] + p.wr2[o + 1048576];
  }
  p.bt[j][(size_t)n * 512 + k] = f2bf(v * 0.25f);
}

// ================= batched layer-1 weight folding (18 jobs) =================
struct FoldPtrs { const float* a[8]; const float* w[2]; u16* bt[4]; };
__constant__ int   c_off[19] = {0,16,24,56,64,320,328,360,368,400,416,424,440,696,704,960,1216,1224,1256};
__constant__ int   c_ai[18]  = {0,1,2,3,4,5,6,7,6, 0,1,0, 4,5,4, 4,5,2};
__constant__ int   c_wi[18]  = {0,0,0,0,0,0,0,0,1, 0,0,1, 0,0,1, 0,0,1};
__constant__ int   c_r0[18]  = {0,0,1,1,2,2,4,4,0, 5,5,5, 6,6,6, 3,3,3};
__constant__ float c_sc[18]  = {0.25f,0.25f,0.25f,0.25f,0.25f,0.25f,0.25f,0.25f,0.25f,
                                1.f,1.f,1.f, 1.f,1.f,1.f, 1.f,1.f,1.f};
__constant__ int   c_bt[18]  = {0,0,0,0,0,0,0,0,0, 1,1,1, 2,2,2, 3,3,3};
__constant__ int   c_K[18]   = {64,64,64,64,64,64,64,64,64, 64,64,64, 128,128,128, 64,64,64};
__constant__ int   c_ko[18]  = {0,2,3,7,8,40,41,45,46, 0,2,3, 0,32,33, 0,32,33};

__global__ __launch_bounds__(256) void fold_multi(FoldPtrs p) {
  __shared__ float red[256];
  int b = blockIdx.x;
  int j = 0;
#pragma unroll
  for (int t = 1; t < 18; ++t) j += (b >= c_off[t]);
  int rel = b - c_off[j];
  int f = rel >> 3, nb = rel & 7;
  int tid = threadIdx.x;
  int n = nb * 64 + (tid & 63);
  int kg = tid >> 6;
  const float* A = p.a[c_ai[j]] + (size_t)f * 512;
  const float* W = p.w[c_wi[j]];
  int k0 = kg * 128;
  float acc = 0.f;
  if (j != 8) {
    const float* Wp = W + (size_t)c_r0[j] * 512 * 512 + n;
#pragma unroll 16
    for (int k = k0; k < k0 + 128; ++k) acc += A[k] * Wp[(size_t)k * 512];
  } else {
    const float* W0 = W + n;
    const float* W1 = W + (size_t)262144 + n;
    const float* W2 = W + (size_t)524288 + n;
    const float* W4 = W + (size_t)1048576 + n;
#pragma unroll 8
    for (int k = k0; k < k0 + 128; ++k) {
      size_t o = (size_t)k * 512;
      acc += A[k] * (W0[o] + W1[o] + W2[o] + W4[o]);
    }
  }
  red[tid] = acc;
  __syncthreads();
  if (kg == 0) {
    float v = red[tid] + red[tid + 64] + red[tid + 128] + red[tid + 192];
    p.bt[c_bt[j]][(size_t)n * c_K[j] + c_ko[j] + f] = f2bf(v * c_sc[j]);
  }
}

// ---- batched bias folds ----
struct VFPtrs { const float* bl[5]; const float* bvec[5]; const float* w; float* out[5]; };
__constant__ int   c_vi[5][4] = {{0,1,2,4},{0,1,2,4},{5,-1,-1,-1},{6,-1,-1,-1},{3,-1,-1,-1}};
__constant__ float c_vs[5]    = {0.25f,0.25f,1.f,1.f,1.f};

__global__ __launch_bounds__(256) void vecfold_multi(VFPtrs p) {
  __shared__ float red[256];
  int j = blockIdx.x >> 4, blk = blockIdx.x & 15;
  int tid = threadIdx.x;
  int n = blk * 32 + (tid & 31);
  int kg = tid >> 5;
  const float* bv = p.bvec[j];
  float a = 0.f;
  if (bv) {
    int i1 = c_vi[j][1];
    const float* W0 = p.w + (size_t)c_vi[j][0] * 262144 + n;
    if (i1 < 0) {
#pragma unroll 16
      for (int k = kg * 64; k < kg * 64 + 64; ++k) a += bv[k] * W0[(size_t)k * 512];
    } else {
      const float* W1 = p.w + (size_t)c_vi[j][1] * 262144 + n;
      const float* W2 = p.w + (size_t)c_vi[j][2] * 262144 + n;
      const float* W3 = p.w + (size_t)c_vi[j][3] * 262144 + n;
#pragma unroll 8
      for (int k = kg * 64; k < kg * 64 + 64; ++k) {
        size_t o = (size_t)k * 512;
        a += bv[k] * (W0[o] + W1[o] + W2[o] + W3[o]);
      }
    }
  }
  red[tid] = a;
  __syncthreads();
  if (kg == 0) {
    float v = 0.f;
#pragma unroll
    for (int q = 0; q < 8; ++q) v += red[(tid & 31) + q * 32];
    float bsum = p.bl[j][c_vi[j][0] * 512 + n];
    if (c_vi[j][1] >= 0) {
      bsum += p.bl[j][c_vi[j][1] * 512 + n];
      bsum += p.bl[j][c_vi[j][2] * 512 + n];
      bsum += p.bl[j][c_vi[j][3] * 512 + n];
    }
    p.out[j][n] = (v + bsum) * c_vs[j];
  }
}

// ================= CSR build (batched) =================
struct EdgePtrs { const int* dst[7]; const int* src[7]; };
__constant__ int c_hoff[8]  = {0,1024,2048,3072,4096,5120,5248,5760};
__constant__ int c_hbase[7] = {0,131072,262144,393216,458752,589824,622592};
__constant__ int c_hne[7]   = {262144,262144,262144,262144,262144,32768,131072};

__global__ __launch_bounds__(256) void hist_multi(EdgePtrs p, int* __restrict__ cnt) {
  int b = blockIdx.x;
  int j = 0;
#pragma unroll
  for (int t = 1; t < 7; ++t) j += (b >= c_hoff[t]);
  int i = (b - c_hoff[j]) * 256 + threadIdx.x;
  if (i < c_hne[j]) atomicAdd(&cnt[c_hbase[j] + p.dst[j][i]], 1);
}

__global__ __launch_bounds__(256) void fill_multi(EdgePtrs p, int* __restrict__ cursor,
                                                  int* __restrict__ esrc) {
  int b = blockIdx.x;
  int j = 0;
#pragma unroll
  for (int t = 1; t < 7; ++t) j += (b >= c_hoff[t]);
  int i = (b - c_hoff[j]) * 256 + threadIdx.x;
  if (i < c_hne[j]) {
    int pos = atomicAdd(&cursor[c_hbase[j] + p.dst[j][i]], 1);
    esrc[pos] = p.src[j][i];
  }
}

__global__ void scan1_k(const int* __restrict__ in, int* __restrict__ out,
                        int* __restrict__ part, int n) {
  __shared__ int s[256];
  int t = threadIdx.x;
  int base = blockIdx.x * 1024 + t * 4;
  int x0 = 0, x1 = 0, x2 = 0, x3 = 0;
  if (base < n) x0 = in[base];
  if (base + 1 < n) x1 = in[base + 1];
  if (base + 2 < n) x2 = in[base + 2];
  if (base + 3 < n) x3 = in[base + 3];
  int tsum = x0 + x1 + x2 + x3;
  s[t] = tsum;
  __syncthreads();
  for (int off = 1; off < 256; off <<= 1) {
    int v = (t >= off) ? s[t - off] : 0;
    __syncthreads();
    s[t] += v;
    __syncthreads();
  }
  int excl = s[t] - tsum;
  if (base < n) out[base] = excl;
  if (base + 1 < n) out[base + 1] = excl + x0;
  if (base + 2 < n) out[base + 2] = excl + x0 + x1;
  if (base + 3 < n) out[base + 3] = excl + x0 + x1 + x2;
  if (t == 255) part[blockIdx.x] = s[255];
}

__global__ void scan2_k(int* __restrict__ part, int nb) {
  __shared__ int s[1024];
  int t = threadIdx.x;
  int orig = (t < nb) ? part[t] : 0;
  s[t] = orig;
  __syncthreads();
  for (int off = 1; off < 1024; off <<= 1) {
    int v = (t >= off) ? s[t - off] : 0;
    __syncthreads();
    s[t] += v;
    __syncthreads();
  }
  if (t < nb) part[t] = s[t] - orig;
}

__global__ void scan3_k(int* __restrict__ out, int* __restrict__ cursor,
                        const int* __restrict__ part, int n) {
  int i = blockIdx.x * 256 + threadIdx.x;
  if (i < n) {
    int v = out[i] + part[i >> 10];
    out[i] = v;
    cursor[i] = v;
  }
}

// ---- raw-feature segment mean + indicator (8 threads per dst row) ----
__global__ void raw_agg(const int* __restrict__ offs, const int* __restrict__ esrc,
                        const float* __restrict__ x, int F, u16* __restrict__ A1,
                        int K, int colOff, int indCol, int nd) {
  int row = blockIdx.x * 32 + (threadIdx.x >> 3);
  if (row >= nd) return;
  int j = threadIdx.x & 7;
  int e0 = offs[row], e1 = offs[row + 1];
  float acc[4] = {0.f, 0.f, 0.f, 0.f};
  for (int e = e0; e < e1; ++e) {
    int s = esrc[e];
#pragma unroll
    for (int u = 0; u < 4; ++u) {
      int f = j + u * 8;
      if (f < F) acc[u] += x[(size_t)s * F + f];
    }
  }
  float inv = (e1 > e0) ? 1.f / (float)(e1 - e0) : 0.f;
#pragma unroll
  for (int u = 0; u < 4; ++u) {
    int f = j + u * 8;
    if (f < F) A1[(size_t)row * K + colOff + f] = f2bf(acc[u] * inv);
  }
  if (j == 0) A1[(size_t)row * K + indCol] = f2bf((e1 > e0) ? 1.f : 0.f);
}

// batched op-stage: 4 jobs x 1024 blocks, K=64, 32768 rows/chunk
struct RawPtrs { const int* offs; const int* esrc; const float* x[4]; u16* A1; };
__constant__ int c_gF[4]    = {2,4,32,4};
__constant__ int c_gco[4]   = {0,3,8,41};
__constant__ int c_gic[4]   = {2,7,40,45};
__constant__ int c_gcsrb[4] = {0,131072,262144,458752};

__global__ __launch_bounds__(256) void raw_multi(RawPtrs p, int s0) {
  int j = blockIdx.x >> 10;
  int row = (blockIdx.x & 1023) * 32 + (threadIdx.x >> 3);
  int jj = threadIdx.x & 7;
  const int* offs = p.offs + c_gcsrb[j] + s0;
  const float* x = p.x[j];
  int F = c_gF[j];
  int e0 = offs[row], e1 = offs[row + 1];
  float acc[4] = {0.f, 0.f, 0.f, 0.f};
  for (int e = e0; e < e1; ++e) {
    int s = p.esrc[e];
#pragma unroll
    for (int u = 0; u < 4; ++u) {
      int f = jj + u * 8;
      if (f < F) acc[u] += x[(size_t)s * F + f];
    }
  }
  float inv = (e1 > e0) ? 1.f / (float)(e1 - e0) : 0.f;
#pragma unroll
  for (int u = 0; u < 4; ++u) {
    int f = jj + u * 8;
    if (f < F) p.A1[(size_t)row * 64 + c_gco[j] + f] = f2bf(acc[u] * inv);
  }
  if (jj == 0) p.A1[(size_t)row * 64 + c_gic[j]] = f2bf((e1 > e0) ? 1.f : 0.f);
}

// ---- copy root raw features into A1 ----
__global__ void a1_root(const float* __restrict__ x, int rowBase, u16* __restrict__ A1,
                        int K, int rootOff, int nd, int lf) {
  int idx = blockIdx.x * 256 + threadIdx.x;
  int i = idx >> lf, f = idx & ((1 << lf) - 1);
  if (i >= nd) return;
  A1[(size_t)i * K + rootOff + f] = f2bf(x[(((size_t)(rowBase + i)) << lf) + f]);
}

// ---- fused gather + acc RMW: acc[dst] (+)= mean over in-range nbrs of hT[src] ----
// wave per dst row; all lanes share the edge loop (uniform), 8 bf16 cols/lane.
template <bool FIRST>
__global__ __launch_bounds__(256) void gather_acc(
    const int* __restrict__ offs, const int* __restrict__ esrc,
    const u16* __restrict__ hT, const float* __restrict__ bias,
    u16* __restrict__ acc, int s0, int s1) {
  int w = blockIdx.x * 4 + (threadIdx.x >> 6);
  int l = threadIdx.x & 63;
  int e0 = offs[w], e1 = offs[w + 1];
  float sum[8] = {0.f, 0.f, 0.f, 0.f, 0.f, 0.f, 0.f, 0.f};
  bool found = false;
  for (int e = e0; e < e1; ++e) {
    int s = esrc[e];
    if (s >= s0 && s < s1) {
      found = true;
      bf16x8 v = *(const bf16x8*)&hT[(size_t)(s - s0) * 512 + l * 8];
#pragma unroll
      for (int j = 0; j < 8; ++j) sum[j] += bf2f((u16)v[j]);
    }
  }
  float inv = (e1 > e0) ? 1.f / (float)(e1 - e0) : 0.f;
  u16* ap = acc + (size_t)w * 512 + l * 8;
  bf16x8 r;
  if (FIRST) {
#pragma unroll
    for (int j = 0; j < 8; ++j) r[j] = (short)f2bf(bias[l * 8 + j] + sum[j] * inv);
    *(bf16x8*)ap = r;
  } else {
    if (!found) return;  // uniform across the wave (same w)
    bf16x8 old = *(const bf16x8*)ap;
#pragma unroll
    for (int j = 0; j < 8; ++j) r[j] = (short)f2bf(bf2f((u16)old[j]) + sum[j] * inv);
    *(bf16x8*)ap = r;
  }
}

// ---- MFMA GEMM: C[M][512] (+)= op(A[M][K] @ BT[512][K]^T + bias), bf16 ----
// Swapped-operand MFMA: lane owns 4 consecutive C columns -> 8-B vector RMW epilogue.
template <bool ELU, bool ACC, int K>
__global__ __launch_bounds__(256) void gemm_k(
    const u16* __restrict__ A, const u16* __restrict__ BT,
    const float* __restrict__ bias, u16* __restrict__ C, int M) {
  __shared__ u16 As[128 * 64];
  __shared__ u16 Bs[128 * 64];
  int tid = threadIdx.x;
  int wid = tid >> 6, lane = tid & 63;
  int wm = wid >> 1, wn = wid & 1;
  int bm = blockIdx.x * 128, bn = blockIdx.y * 128;
  int r16 = lane & 15, hi4 = lane >> 4;
  int srow = tid >> 3;
  int scol = ((tid & 7) ^ (srow & 7)) * 8;  // pre-swizzled source column group
  int sw = r16 & 7;                          // read-side XOR key
  f32x4 acc[4][4];
#pragma unroll
  for (int i = 0; i < 4; ++i)
#pragma unroll
    for (int j = 0; j < 4; ++j) acc[i][j] = (f32x4){0.f, 0.f, 0.f, 0.f};

#pragma unroll
  for (int k0 = 0; k0 < K; k0 += 64) {
    __syncthreads();
#pragma unroll
    for (int i = 0; i < 4; ++i) {
      const u16* ga = A + (size_t)(bm + i * 32 + srow) * K + k0 + scol;
      const u16* gb = BT + (size_t)(bn + i * 32 + srow) * K + k0 + scol;
      __builtin_amdgcn_global_load_lds((gv_t*)ga, (lv_t*)(As + i * 2048 + wid * 512), 16, 0, 0);
      __builtin_amdgcn_global_load_lds((gv_t*)gb, (lv_t*)(Bs + i * 2048 + wid * 512), 16, 0, 0);
    }
    __syncthreads();
#pragma unroll
    for (int kk = 0; kk < 64; kk += 32) {
      bf16x8 af[4], bfr[4];
#pragma unroll
      for (int f = 0; f < 4; ++f) {
        int grp = (kk >> 3) + hi4;
        af[f]  = *(const bf16x8*)&As[(wm * 64 + f * 16 + r16) * 64 + ((grp ^ sw) << 3)];
        bfr[f] = *(const bf16x8*)&Bs[(wn * 64 + f * 16 + r16) * 64 + ((grp ^ sw) << 3)];
      }
#pragma unroll
      for (int mf = 0; mf < 4; ++mf)
#pragma unroll
        for (int nf = 0; nf < 4; ++nf)
          acc[mf][nf] = __builtin_amdgcn_mfma_f32_16x16x32_bf16(bfr[nf], af[mf], acc[mf][nf], 0, 0, 0);
    }
  }
#pragma unroll
  for (int mf = 0; mf < 4; ++mf) {
    int r = bm + wm * 64 + mf * 16 + r16;
#pragma unroll
    for (int nf = 0; nf < 4; ++nf) {
      int c0 = bn + wn * 64 + nf * 16 + hi4 * 4;
      u16* cp = C + (size_t)r * 512 + c0;
      bf16x4 oldv;
      if (ACC) oldv = *(const bf16x4*)cp;
      f32x4 bv;
      if (bias) bv = *(const f32x4*)&bias[c0];
      bf16x4 res;
#pragma unroll
      for (int j = 0; j < 4; ++j) {
        float v = acc[mf][nf][j] + (bias ? bv[j] : 0.f);
        if (ACC) v += bf2f((u16)oldv[j]);
        if (ELU) v = v > 0.f ? v : expm1f(v);
        res[j] = (short)f2bf(v);
      }
      *(bf16x4*)cp = res;
    }
  }
}

// ---- LayerNorm in place (wave per row) ----
__global__ void ln_rows(u16* __restrict__ H, const float* __restrict__ g,
                        const float* __restrict__ be, int rows) {
  int w = blockIdx.x * 4 + (threadIdx.x >> 6);
  if (w >= rows) return;
  int l = threadIdx.x & 63;
  u16* p = H + (size_t)w * 512 + l * 8;
  bf16x8 v = *(const bf16x8*)p;
  float x[8];
  float s = 0.f;
#pragma unroll
  for (int j = 0; j < 8; ++j) { x[j] = bf2f((u16)v[j]); s += x[j]; }
#pragma unroll
  for (int m = 1; m < 64; m <<= 1) s += __shfl_xor(s, m, 64);
  float mean = s * (1.f / 512.f);
  float q = 0.f;
#pragma unroll
  for (int j = 0; j < 8; ++j) { float d = x[j] - mean; q += d * d; }
#pragma unroll
  for (int m = 1; m < 64; m <<= 1) q += __shfl_xor(q, m, 64);
  float rsd = rsqrtf(q * (1.f / 512.f) + 1e-5f);
  bf16x8 r;
#pragma unroll
  for (int j = 0; j < 8; ++j) {
    int c = l * 8 + j;
    r[j] = (short)f2bf((x[j] - mean) * rsd * g[c] + be[c]);
  }
  *(bf16x8*)p = r;
}

// ---- fused ELU + LN2 + pool partial-sum ----
DEVINL int lowb(const int* a, int n, int v) {
  int lo = 0, hi = n;
  while (lo < hi) { int m = (lo + hi) >> 1; if (a[m] < v) lo = m + 1; else hi = m; }
  return lo;
}

__global__ __launch_bounds__(256) void pool1v(const u16* __restrict__ H,
                                              const int* __restrict__ batch, int nOp,
                                              const float* __restrict__ g2,
                                              const float* __restrict__ be2,
                                              float* __restrict__ pooled,
                                              int* __restrict__ cnts) {
  __shared__ float red[4][512];
  int gr = blockIdx.x >> 4, part = blockIdx.x & 15;
  int lo = lowb(batch, nOp, gr), hi = lowb(batch, nOp, gr + 1);
  if (part == 0 && threadIdx.x == 0) cnts[gr] = hi - lo;
  int len = hi - lo;
  int chunk = (len + 15) >> 4;
  int r0 = lo + part * chunk;
  int r1 = r0 + chunk;
  if (r1 > hi) r1 = hi;
  int wv = threadIdx.x >> 6, l = threadIdx.x & 63;
  float a[8] = {0.f, 0.f, 0.f, 0.f, 0.f, 0.f, 0.f, 0.f};
  float gv[8], bv[8];
#pragma unroll
  for (int j = 0; j < 8; ++j) { gv[j] = g2[l * 8 + j]; bv[j] = be2[l * 8 + j]; }
  for (int r = r0 + wv; r < r1; r += 4) {
    bf16x8 v = *(const bf16x8*)&H[(size_t)r * 512 + l * 8];
    float x[8];
    float s = 0.f;
#pragma unroll
    for (int j = 0; j < 8; ++j) {
      x[j] = bf2f((u16)v[j]);
      x[j] = x[j] > 0.f ? x[j] : expm1f(x[j]);
      s += x[j];
    }
#pragma unroll
    for (int m = 1; m < 64; m <<= 1) s += __shfl_xor(s, m, 64);
    float mean = s * (1.f / 512.f);
    float q = 0.f;
#pragma unroll
    for (int j = 0; j < 8; ++j) { float d = x[j] - mean; q += d * d; }
#pragma unroll
    for (int m = 1; m < 64; m <<= 1) q += __shfl_xor(q, m, 64);
    float rsd = rsqrtf(q * (1.f / 512.f) + 1e-5f);
#pragma unroll
    for (int j = 0; j < 8; ++j) a[j] += (x[j] - mean) * rsd * gv[j] + bv[j];
  }
#pragma unroll
  for (int j = 0; j < 8; ++j) red[wv][l * 8 + j] = a[j];
  __syncthreads();
  if (wv == 0) {
#pragma unroll
    for (int j = 0; j < 8; ++j) {
      int c = l * 8 + j;
      float s = red[0][c] + red[1][c] + red[2][c] + red[3][c];
      atomicAdd(&pooled[gr * 512 + c], s);
    }
  }
}

__global__ void pool2(const float* __restrict__ pooled, const int* __restrict__ cnts,
                      const float* __restrict__ Wout, const float* __restrict__ bout,
                      float* __restrict__ out) {
  int gg = blockIdx.x;
  int l = threadIdx.x;
  float s = 0.f;
#pragma unroll
  for (int j = 0; j < 8; ++j) {
    int c = l * 8 + j;
    s += pooled[gg * 512 + c] * Wout[c];
  }
#pragma unroll
  for (int m = 1; m < 64; m <<= 1) s += __shfl_xor(s, m, 64);
  if (l == 0) {
    int c = cnts[gg];
    if (c < 1) c = 1;
    out[gg] = s / (float)c + bout[0];
  }
}

extern "C" void kernel_launch(void* const* d_in, const int* in_sizes, int n_in,
                              void* d_out, int out_size, void* d_ws, size_t ws_size,
                              hipStream_t stream) {
  (void)in_sizes; (void)n_in; (void)out_size;
  const float* x_op   = (const float*)d_in[0];
  const float* x_tab  = (const float*)d_in[1];
  const float* x_col  = (const float*)d_in[2];
  const float* x_pred = (const float*)d_in[3];
  const float* W_op = (const float*)d_in[4],  *b_op = (const float*)d_in[5];
  const float* W_tab = (const float*)d_in[6], *b_tab = (const float*)d_in[7];
  const float* W_col = (const float*)d_in[8], *b_col = (const float*)d_in[9];
  const float* W_pred = (const float*)d_in[10], *b_pred = (const float*)d_in[11];
  const float* Wl1 = (const float*)d_in[12];
  const float* bl1 = (const float*)d_in[13];
  const float* Wr1 = (const float*)d_in[14];
  const float* Wl2 = (const float*)d_in[15];
  const float* bl2 = (const float*)d_in[16];
  const float* Wr2 = (const float*)d_in[17];
  const float* g1  = (const float*)d_in[18];
  const float* be1 = (const float*)d_in[19];
  const float* g2  = (const float*)d_in[20];
  const float* be2 = (const float*)d_in[21];
  const float* Wout = (const float*)d_in[22];
  const float* bout = (const float*)d_in[23];
  const int* SRC[7], *DST[7];
  for (int r = 0; r < 7; ++r) { SRC[r] = (const int*)d_in[24 + 2 * r]; DST[r] = (const int*)d_in[25 + 2 * r]; }
  const int* batch = (const int*)d_in[38];
  float* out = (float*)d_out;

  const int CSRB[7] = {0, 131072, 262144, 393216, 458752, 589824, 622592};
  const int TOT = 753664;
  const int NOP = 131072;

  // ---- workspace layout (<=249 MB) ----
  char* ws = (char*)d_ws;
  u16* acc     = (u16*)ws;                          // 134,217,728 : conv2 accumulator
  u16* h1      = (u16*)(ws + 134217728ull);         //  33,554,432 : layer-1 chunk (32768 rows)
  int* curFul  = (int*)(ws + 134217728ull);         //   (overlay: CSR cursor, dead later)
  u16* hT      = (u16*)(ws + 167772160ull);         //  67,108,864 : transformed chunk x2
  u16* A1      = (u16*)(ws + 234881024ull);         //   8,388,608 : [32768x128] features
  int* offsFul = (int*)(ws + 243269632ull);         //   3,014,912
  int* esrcFul = (int*)(ws + 246284544ull);         //   5,898,240
  u16* BT2_0   = (u16*)(ws + 252182784ull);         //   5 x 524,288
  u16* BT2_1   = BT2_0 + 262144;
  u16* BT2_2   = BT2_1 + 262144;
  u16* BT2_4   = BT2_2 + 262144;
  u16* BT2rt   = BT2_4 + 262144;
  u16* BT1op   = (u16*)(ws + 254804224ull);         //      65,536
  u16* BT1tab  = (u16*)(ws + 254869760ull);         //      65,536
  u16* BT1col  = (u16*)(ws + 254935296ull);         //     131,072
  u16* BT1pr   = (u16*)(ws + 255066368ull);         //      65,536
  float* b1op  = (float*)(ws + 255131904ull);       //   5 x 2048
  float* b1tab = b1op + 512, *b1col = b1op + 1024, *b1pr = b1op + 1536, *b2vec = b1op + 2048;
  float* pooled = (float*)(ws + 255142144ull);      //     131,072
  int* cnts     = (int*)(ws + 255273216ull);        //         256
  int* part     = (int*)(ws + 255273472ull);        //       4,096
  const size_t WS_NEED = 255277568ull;
  if (ws_size < WS_NEED) { probe_k<<<1, 64, 0, stream>>>(out, (float)ws_size); return; }

  // ---- A. full CSR (7 rels), cursor overlaid in h1 region ----
  (void)hipMemsetAsync(curFul, 0, 3014912ull, stream);
  EdgePtrs ep;
  for (int r = 0; r < 7; ++r) { ep.dst[r] = DST[r]; ep.src[r] = SRC[r]; }
  hist_multi<<<5760, 256, 0, stream>>>(ep, curFul);
  scan1_k<<<737, 256, 0, stream>>>(curFul, offsFul, part, TOT + 1);
  scan2_k<<<1, 1024, 0, stream>>>(part, 737);
  scan3_k<<<2945, 256, 0, stream>>>(offsFul, curFul, part, TOT + 1);
  fill_multi<<<5760, 256, 0, stream>>>(ep, curFul, esrcFul);

  // ---- B. weight folding ----
  PackPtrs pp;
  pp.wl2 = Wl2; pp.wr2 = Wr2;
  pp.bt[0] = BT2_0; pp.bt[1] = BT2_1; pp.bt[2] = BT2_2; pp.bt[3] = BT2_4; pp.bt[4] = BT2rt;
  pack_multi<<<5120, 256, 0, stream>>>(pp);
  (void)hipMemsetAsync(BT1op, 0, 65536 + 65536 + 131072 + 65536, stream);
  FoldPtrs fp;
  fp.a[0] = W_tab; fp.a[1] = b_tab; fp.a[2] = W_pred; fp.a[3] = b_pred;
  fp.a[4] = W_col; fp.a[5] = b_col; fp.a[6] = W_op;   fp.a[7] = b_op;
  fp.w[0] = Wl1;   fp.w[1] = Wr1;
  fp.bt[0] = BT1op; fp.bt[1] = BT1tab; fp.bt[2] = BT1col; fp.bt[3] = BT1pr;
  fold_multi<<<1256, 256, 0, stream>>>(fp);
  VFPtrs vp;
  vp.bl[0] = bl2; vp.bl[1] = bl1; vp.bl[2] = bl1; vp.bl[3] = bl1; vp.bl[4] = bl1;
  vp.bvec[0] = nullptr; vp.bvec[1] = b_op; vp.bvec[2] = b_tab; vp.bvec[3] = b_col; vp.bvec[4] = b_pred;
  vp.w = Wr1;
  vp.out[0] = b2vec; vp.out[1] = b1op; vp.out[2] = b1tab; vp.out[3] = b1col; vp.out[4] = b1pr;
  vecfold_multi<<<80, 256, 0, stream>>>(vp);

  // ---- C. tab (rel0), single 32768-chunk; FIRST gather initializes acc ----
  (void)hipMemsetAsync(A1, 0, 32768ull * 64 * 2, stream);
  raw_agg<<<1024, 256, 0, stream>>>(offsFul + CSRB[5], esrcFul, x_tab, 2, A1, 64, 0, 2, 32768);
  a1_root<<<256, 256, 0, stream>>>(x_tab, 0, A1, 64, 3, 32768, 1);
  gemm_k<true, false, 64><<<dim3(256, 4), 256, 0, stream>>>(A1, BT1tab, b1tab, h1, 32768);
  ln_rows<<<8192, 256, 0, stream>>>(h1, g1, be1, 32768);
  gemm_k<false, false, 512><<<dim3(256, 4), 256, 0, stream>>>(h1, BT2_0, nullptr, hT, 32768);
  gather_acc<true><<<32768, 256, 0, stream>>>(offsFul + CSRB[0], esrcFul, hT, b2vec, acc, 0, 32768);

  // ---- D. pred (rel1), 2 quarters -> hT, one whole-range gather ----
  (void)hipMemsetAsync(A1, 0, 32768ull * 64 * 2, stream);
  for (int q = 0; q < 2; ++q) {
    int qs = q * 32768;
    raw_agg<<<1024, 256, 0, stream>>>(offsFul + CSRB[3] + qs, esrcFul, x_col, 32, A1, 64, 0, 32, 32768);
    a1_root<<<512, 256, 0, stream>>>(x_pred, qs, A1, 64, 33, 32768, 2);
    gemm_k<true, false, 64><<<dim3(256, 4), 256, 0, stream>>>(A1, BT1pr, b1pr, h1, 32768);
    ln_rows<<<8192, 256, 0, stream>>>(h1, g1, be1, 32768);
    gemm_k<false, false, 512><<<dim3(256, 4), 256, 0, stream>>>(h1, BT2_1, nullptr,
                                                                hT + (size_t)qs * 512, 32768);
  }
  gather_acc<false><<<32768, 256, 0, stream>>>(offsFul + CSRB[1], esrcFul, hT, nullptr, acc, 0, 65536);

  // ---- E. col (rel2), 2 super-halves x 2 quarters ----
  (void)hipMemsetAsync(A1, 0, 32768ull * 128 * 2, stream);
  for (int hs = 0; hs < 2; ++hs) {
    int S0 = hs * 65536;
    for (int q = 0; q < 2; ++q) {
      int qs = S0 + q * 32768;
      raw_agg<<<1024, 256, 0, stream>>>(offsFul + CSRB[6] + qs, esrcFul, x_col, 32, A1, 128, 0, 32, 32768);
      a1_root<<<4096, 256, 0, stream>>>(x_col, qs, A1, 128, 33, 32768, 5);
      gemm_k<true, false, 128><<<dim3(256, 4), 256, 0, stream>>>(A1, BT1col, b1col, h1, 32768);
      ln_rows<<<8192, 256, 0, stream>>>(h1, g1, be1, 32768);
      gemm_k<false, false, 512><<<dim3(256, 4), 256, 0, stream>>>(h1, BT2_2, nullptr,
                                                                  hT + (size_t)q * 32768 * 512, 32768);
    }
    gather_acc<false><<<32768, 256, 0, stream>>>(offsFul + CSRB[2], esrcFul, hT, nullptr,
                                                 acc, S0, S0 + 65536);
  }

  // ---- F. op (rel4 + root), 2 super-halves x 2 quarters ----
  (void)hipMemsetAsync(A1, 0, 32768ull * 64 * 2, stream);
  for (int hs = 0; hs < 2; ++hs) {
    int S0 = hs * 65536;
    for (int q = 0; q < 2; ++q) {
      int qs = S0 + q * 32768;
      RawPtrs rp;
      rp.offs = offsFul; rp.esrc = esrcFul; rp.A1 = A1;
      rp.x[0] = x_tab; rp.x[1] = x_pred; rp.x[2] = x_col; rp.x[3] = x_op;
      raw_multi<<<4096, 256, 0, stream>>>(rp, qs);
      a1_root<<<512, 256, 0, stream>>>(x_op, qs, A1, 64, 46, 32768, 2);
      gemm_k<true, false, 64><<<dim3(256, 4), 256, 0, stream>>>(A1, BT1op, b1op, h1, 32768);
      ln_rows<<<8192, 256, 0, stream>>>(h1, g1, be1, 32768);
      // root contribution: acc[qs..qs+32768) += h1 @ BT2rt
      gemm_k<false, true, 512><<<dim3(256, 4), 256, 0, stream>>>(h1, BT2rt, nullptr,
                                                                 acc + (size_t)qs * 512, 32768);
      gemm_k<false, false, 512><<<dim3(256, 4), 256, 0, stream>>>(h1, BT2_4, nullptr,
                                                                  hT + (size_t)q * 32768 * 512, 32768);
    }
    gather_acc<false><<<32768, 256, 0, stream>>>(offsFul + CSRB[4], esrcFul, hT, nullptr,
                                                 acc, S0, S0 + 65536);
  }

  // ---- G. fused ELU + LN2 + pool, then output ----
  (void)hipMemsetAsync(pooled, 0, 64 * 512 * 4, stream);
  pool1v<<<1024, 256, 0, stream>>>(acc, batch, NOP, g2, be2, pooled, cnts);
  pool2<<<64, 64, 0, stream>>>(pooled, cnts, Wout, bout, out);
}